// Round 13
// baseline (271.335 us; speedup 1.0000x reference)
//
#include <hip/hip_runtime.h>

#define DI static __device__ __forceinline__

typedef __attribute__((ext_vector_type(8))) short s8v;
typedef __attribute__((ext_vector_type(4))) short s4v;
typedef __attribute__((ext_vector_type(4))) float f4v;

DI short f2b(float x) {
  unsigned u = __builtin_bit_cast(unsigned, x);
  u = (u + 0x7fffu + ((u >> 16) & 1u)) >> 16;
  return (short)u;
}
DI float b2f(short s) {
  unsigned u = ((unsigned)(unsigned short)s) << 16;
  return __builtin_bit_cast(float, u);
}
DI f4v mfma16(s8v a, s8v b, f4v c) {
  return __builtin_amdgcn_mfma_f32_16x16x32_bf16(a, b, c, 0, 0, 0);
}
DI void gload16(const short* g, short* l) {
  __builtin_amdgcn_global_load_lds(
      (const __attribute__((address_space(1))) unsigned*)g,
      (__attribute__((address_space(3))) unsigned*)l, 16, 0, 0);
}

// ---------------- batched f32 -> bf16 convert (4 weight matrices) ----------------
__global__ __launch_bounds__(256) void cvtw4_k(
    const float* __restrict__ s0, const float* __restrict__ s1,
    const float* __restrict__ s2, const float* __restrict__ s3,
    short* __restrict__ d0, short* __restrict__ d1,
    short* __restrict__ d2, short* __restrict__ d3) {
  int w = blockIdx.y;
  const float* s = (w == 0) ? s0 : (w == 1) ? s1 : (w == 2) ? s2 : s3;
  short* d = (w == 0) ? d0 : (w == 1) ? d1 : (w == 2) ? d2 : d3;
  int i = blockIdx.x * 256 + threadIdx.x;
  d[i] = f2b(s[i]);
}

// ---------------- grouped 9x9 stride-2 conv (offset net part 1) ----------------
__global__ __launch_bounds__(256) void conv_off_k(
    const float* __restrict__ x, const float* __restrict__ y,
    const float* __restrict__ w1, const float* __restrict__ b1,
    float* __restrict__ co)
{
  __shared__ float si[8 * 8 * 84 + 84];   // 21.8 kB; zero row at offset 5376
  const int cc = blockIdx.x;
  const int n  = blockIdx.y;
  const int b = n >> 2, g = n & 3;
  const int c0 = cc * 8;
  const float* src = (g < 2 ? x : y) + ((size_t)b * 640 + (g & 1) * 320 + c0) * 512;
  const int tid = threadIdx.x;
  float* const zb = &si[8 * 8 * 84];

  for (int i = tid; i < 512; i += 256) {
    int chrow = i >> 3, t = i & 7;
    int par = t & 1, which = t >> 1;
    int idx = (which < 2) ? which : 32 + which;
    si[chrow * 84 + par * 42 + idx] = 0.f;
  }
  for (int i = tid; i < 84; i += 256) zb[i] = 0.f;
  for (int i = tid; i < 8 * 512; i += 256) {
    int ch = i >> 9, idx = i & 511;
    int r = idx >> 6, c = idx & 63;
    int pc = c + 4;
    si[(ch * 8 + r) * 84 + (pc & 1) * 42 + (pc >> 1)] = src[(size_t)ch * 512 + idx];
  }
  __syncthreads();

  const int lane = tid & 63, wvi = tid >> 6;
  const int cl = lane & 15, rg = lane >> 4;
  const int ocs = __builtin_amdgcn_readfirstlane(c0 + 2 * wvi);
  const float* wbase = w1 + (size_t)ocs * 162;
  float a00 = 0.f, a01 = 0.f, a10 = 0.f, a11 = 0.f;
#pragma unroll
  for (int ic = 0; ic < 2; ++ic) {
    const float* chb = &si[(2 * wvi + ic) * 8 * 84];
#pragma unroll
    for (int kh = 0; kh < 9; ++kh) {
      const int row = 2 * rg + kh - 4;
      const float* rp = ((unsigned)row < 8u) ? (chb + row * 84) : zb;
      float ev[6], ov[5];
#pragma unroll
      for (int t = 0; t < 6; ++t) ev[t] = rp[2 * cl + t];
#pragma unroll
      for (int t = 0; t < 5; ++t) ov[t] = rp[42 + 2 * cl + t];
      const float* wv0 = wbase + ic * 81 + kh * 9;
      const float* wv1 = wv0 + 162;
#pragma unroll
      for (int kw = 0; kw < 9; ++kw) {
        float w0 = wv0[kw], w1v = wv1[kw];
        int j = kw >> 1;
        float v0 = (kw & 1) ? ov[j] : ev[j];
        float v1 = (kw & 1) ? ov[j + 1] : ev[j + 1];
        a00 = fmaf(v0, w0, a00);
        a01 = fmaf(v1, w0, a01);
        a10 = fmaf(v0, w1v, a10);
        a11 = fmaf(v1, w1v, a11);
      }
    }
  }
  const float bv0 = b1[ocs], bv1 = b1[ocs + 1];
  const int s0 = rg * 32 + 2 * cl;
  float2 vA = {a00 + bv0, a10 + bv1};
  float2 vB = {a01 + bv0, a11 + bv1};
  *(float2*)&co[((size_t)n * 128 + s0) * 320 + ocs] = vA;
  *(float2*)&co[((size_t)n * 128 + s0 + 1) * 320 + ocs] = vB;
}

// ---------------- LN + GELU + proj + tanh -> pos (offset net part 2) ----------------
__global__ __launch_bounds__(256) void ln_proj_k(
    const float* __restrict__ co, const float* __restrict__ lng,
    const float* __restrict__ lnb, const float* __restrict__ w2,
    float* __restrict__ pos, float* __restrict__ pos_out, float* __restrict__ ref_out)
{
  const int n = blockIdx.y;
  const int wvi = threadIdx.x >> 6, lane = threadIdx.x & 63;
  const int s = blockIdx.x * 4 + wvi;
  const float* cp = co + ((size_t)n * 128 + s) * 320;
  float v[5], gw[5], gb[5], p0[5], p1[5];
#pragma unroll
  for (int t = 0; t < 5; ++t) {
    int ch = lane + 64 * t;
    v[t] = cp[ch]; gw[t] = lng[ch]; gb[t] = lnb[ch];
    p0[t] = w2[ch]; p1[t] = w2[320 + ch];
  }
  float s1 = 0.f, s2 = 0.f;
#pragma unroll
  for (int t = 0; t < 5; ++t) { s1 += v[t]; s2 += v[t] * v[t]; }
#pragma unroll
  for (int o = 32; o; o >>= 1) { s1 += __shfl_xor(s1, o); s2 += __shfl_xor(s2, o); }
  float mu = s1 * (1.f / 320.f);
  float var = s2 * (1.f / 320.f) - mu * mu;
  float rstd = rsqrtf(var + 1e-5f);
  float d0 = 0.f, d1 = 0.f;
#pragma unroll
  for (int t = 0; t < 5; ++t) {
    float xn = (v[t] - mu) * rstd * gw[t] + gb[t];
    float ge = 0.5f * xn * (1.f + erff(xn * 0.70710678118654752f));
    d0 = fmaf(ge, p0[t], d0);
    d1 = fmaf(ge, p1[t], d1);
  }
#pragma unroll
  for (int o = 32; o; o >>= 1) { d0 += __shfl_xor(d0, o); d1 += __shfl_xor(d1, o); }
  if (lane == 0) {
    float oy = tanhf(d0) * 0.5f;
    float ox = tanhf(d1) * 0.0625f;
    int hk = s >> 5, wk = s & 31;
    float ry = ((float)hk + 0.5f) * 0.5f - 1.f;
    float rx = ((float)wk + 0.5f) * 0.0625f - 1.f;
    float py = oy + ry, px = ox + rx;
    size_t o2 = ((size_t)n * 128 + s) * 2;
    pos[o2] = py;     pos[o2 + 1] = px;
    pos_out[o2] = py; pos_out[o2 + 1] = px;
    ref_out[o2] = ry; ref_out[o2 + 1] = rx;
  }
}

// ---------------- transpose both x,y: [b][c][hw] f32 -> [b][hw][c] bf16 ----------------
__global__ __launch_bounds__(256) void transpose_k(
    const float* __restrict__ x, const float* __restrict__ y,
    short* __restrict__ xt, short* __restrict__ yt) {
  __shared__ float tile[32][33];
  const int ct = blockIdx.x, st = blockIdx.y, z = blockIdx.z;
  const int b = z & 31;
  const float* srcm = (z < 32) ? x : y;
  short* dstm = (z < 32) ? xt : yt;
  const int tx = threadIdx.x, ty = threadIdx.y;
  const float* src = srcm + ((size_t)b * 640 + ct * 32) * 512 + st * 32;
#pragma unroll
  for (int k2 = 0; k2 < 4; ++k2)
    tile[ty + 8 * k2][tx] = src[(size_t)(ty + 8 * k2) * 512 + tx];
  __syncthreads();
  short* dst = dstm + ((size_t)b * 512 + st * 32) * 640 + ct * 32;
#pragma unroll
  for (int k2 = 0; k2 < 4; ++k2)
    dst[(size_t)(ty + 8 * k2) * 640 + tx] = f2b(tile[tx][ty + 8 * k2]);
}

// ---------------- bilinear sampler: xs[b][n=128][c=640] bf16 ----------------
__global__ __launch_bounds__(256) void sample_k(const short* __restrict__ xt,
                                                const float* __restrict__ pos,
                                                short* __restrict__ xs) {
  const int sc = blockIdx.x, bg = blockIdx.y;
  const int b = bg >> 2, g = bg & 3;
  const int t = threadIdx.x;
  const int s = sc * 8 + (t >> 5);
  const int ci = t & 31;
  size_t p2 = ((size_t)bg * 128 + s) * 2;
  float py = pos[p2], px = pos[p2 + 1];
  float gx = (px + 1.f) * 32.f - 0.5f;
  float gy = (py + 1.f) * 4.f - 0.5f;
  float fx = floorf(gx), fy = floorf(gy);
  int x0 = (int)fx, y0 = (int)fy;
  float wx1 = gx - fx, wx0 = 1.f - wx1;
  float wy1 = gy - fy, wy0 = 1.f - wy1;
  int xx[2] = {x0, x0 + 1}, yy[2] = {y0, y0 + 1};
  float wxs[2] = {wx0, wx1}, wys[2] = {wy0, wy1};
  const short* basep = xt + (size_t)b * 512 * 640 + (size_t)g * 160;
  short* outp = xs + ((size_t)(b * 128 + s)) * 640 + g * 160;
#pragma unroll
  for (int kk = 0; kk < 5; ++kk) {
    int c = kk * 32 + ci;
    float acc = 0.f;
#pragma unroll
    for (int ty = 0; ty < 2; ++ty) {
      int yv = yy[ty];
      bool vy = (yv >= 0) & (yv < 8);
      int yc = min(max(yv, 0), 7);
#pragma unroll
      for (int tx = 0; tx < 2; ++tx) {
        int xv = xx[tx];
        bool vv = vy & (xv >= 0) & (xv < 64);
        int xc = min(max(xv, 0), 63);
        float val = b2f(basep[((size_t)yc * 64 + xc) * 640 + c]);
        acc += wys[ty] * wxs[tx] * (vv ? val : 0.f);
      }
    }
    outp[c] = f2b(acc);
  }
}

// ---------------- 128x128-tile MFMA GEMM with global_load_lds (m97 structure) ----
template <bool BIASN, bool OUTF32>
__global__ __launch_bounds__(256) void gemm128_k(
    const short* __restrict__ W, long long wStride,
    const short* __restrict__ X, long long xStride,
    const float* __restrict__ bias, void* __restrict__ Out,
    int M, int K, int N)
{
  __shared__ short wa[128 * 32];
  __shared__ short xb[128 * 32];
  const int m0 = blockIdx.x * 128, n0 = blockIdx.y * 128;
  const int bz = blockIdx.z;
  const short* Wp = W + (size_t)bz * wStride + (size_t)m0 * K;
  const short* Xp = X + (size_t)bz * xStride + (size_t)n0 * K;
  const int tid = threadIdx.x;
  const int lane = tid & 63;
  const int wvi = __builtin_amdgcn_readfirstlane(tid >> 6);
  const int wr = wvi >> 1, wc = wvi & 1, lr = lane & 15, lg = lane >> 4;

  const int r0 = (wvi * 16) + (lane >> 2);
  const int cb = (lane & 3) * 8;
  const short* wg0 = Wp + (size_t)r0 * K + cb;
  const short* wg1 = Wp + (size_t)(r0 + 64) * K + cb;
  const short* xg0 = Xp + (size_t)r0 * K + cb;
  const short* xg1 = Xp + (size_t)(r0 + 64) * K + cb;
  short* la0 = &wa[wvi * 512];
  short* la1 = &wa[(4 + wvi) * 512];
  short* lb0 = &xb[wvi * 512];
  short* lb1 = &xb[(4 + wvi) * 512];

  f4v acc[4][4];
#pragma unroll
  for (int i = 0; i < 4; ++i)
#pragma unroll
    for (int j = 0; j < 4; ++j) acc[i][j] = (f4v)0.0f;

  const int nk = K >> 5;
  for (int ks = 0; ks < nk; ++ks) {
    __syncthreads();
    const int ko = ks * 32;
    gload16(wg0 + ko, la0);
    gload16(wg1 + ko, la1);
    gload16(xg0 + ko, lb0);
    gload16(xg1 + ko, lb1);
    __syncthreads();
    s8v av[4], bv[4];
#pragma unroll
    for (int i = 0; i < 4; ++i)
      av[i] = *(const s8v*)&wa[(wr * 64 + i * 16 + lr) * 32 + lg * 8];
#pragma unroll
    for (int j = 0; j < 4; ++j)
      bv[j] = *(const s8v*)&xb[(wc * 64 + j * 16 + lr) * 32 + lg * 8];
#pragma unroll
    for (int i = 0; i < 4; ++i)
#pragma unroll
      for (int j = 0; j < 4; ++j)
        acc[i][j] = mfma16(av[i], bv[j], acc[i][j]);
  }

#pragma unroll
  for (int i = 0; i < 4; ++i)
#pragma unroll
    for (int j = 0; j < 4; ++j)
#pragma unroll
      for (int r = 0; r < 4; ++r) {
        int m_g = m0 + wr * 64 + i * 16 + lg * 4 + r;
        int n_g = n0 + wc * 64 + j * 16 + lr;
        float val = acc[i][j][r] + (BIASN ? bias[n_g] : bias[m_g]);
        size_t oidx = (size_t)bz * M * N + (size_t)m_g * N + n_g;
        if (OUTF32) ((float*)Out)[oidx] = val;
        else        ((short*)Out)[oidx] = f2b(val);
      }
}

// ---------------- fused QK^T + RPE bias + softmax + PV -> ao_t (bf16) -------------
// Swapped QK (lane-local softmax rows). V from GLOBAL via volatile (defeats the
// 80-VGPR loop-invariant hoist); bias tables read volatile (defeats 64-VGPR hoist);
// RPE table in bf16 (5.5 kB). LDS ~50.6 kB -> 3 blocks/CU.
__global__ __launch_bounds__(256) void qkpv_k(
    const short* __restrict__ q_t, const short* __restrict__ k_t,
    const short* __restrict__ v_, const float* __restrict__ pos,
    const float* __restrict__ rpe, short* __restrict__ ao_t)
{
  __shared__ short kT[128 * 104];     // 26.6 kB
  __shared__ short pT[64 * 136];      // 17.4 kB (wave-private 16-row bands)
  __shared__ short rpeB[21 * 132];    // 5.5 kB bf16, zero-padded ring of 3
  __shared__ float pynL[128], pxnL[128];
  const int bh = blockIdx.x, mh = blockIdx.y;
  const int b = bh >> 3, h = bh & 7, g = h >> 1;
  const int bg = b * 4 + g;
  const int tid = threadIdx.x;
  const int lane = tid & 63, wvi = tid >> 6;
  const int lr = lane & 15, lg = lane >> 4;

  // ---- stage once per block ----
  for (int i = tid; i < 21 * 132; i += 256) rpeB[i] = 0;
  if (tid < 128) {
    float py = pos[(size_t)bg * 256 + tid * 2];
    float px = pos[(size_t)bg * 256 + tid * 2 + 1];
    pynL[tid] = 10.0f - py * 3.75f;
    pxnL[tid] = 66.0f - px * 31.75f;
  }
  const short* kp = k_t + (size_t)b * 128 * 640 + h * 80;
  for (int idx = tid; idx < 1280; idx += 256) {
    int row = idx / 10, cb = idx - row * 10;
    *(s8v*)&kT[row * 104 + cb * 8] = *(const s8v*)&kp[(size_t)row * 640 + cb * 8];
  }
  for (int idx = tid; idx < 384; idx += 256) {
    int row = idx / 3, cb = idx - row * 3;
    *(s8v*)&kT[row * 104 + 80 + cb * 8] = (s8v)(short)0;
  }
  __syncthreads();
  for (int i = tid; i < 15 * 127; i += 256) {
    int r = i / 127, c = i - r * 127;
    rpeB[(r + 3) * 132 + (c + 3)] = f2b(rpe[(size_t)h * (15 * 127) + i]);
  }
  __syncthreads();

  const float scale = 0.11180339887498949f;  // 80^-0.5
  const short* qbase = q_t + ((size_t)b * 512 + mh * 256 + wvi * 16) * 640 + h * 80;
  const short* vp = v_ + ((size_t)b * 640 + h * 80) * 128;
  short* aobase = ao_t + ((size_t)b * 512 + mh * 256 + wvi * 16) * 640 + h * 80;

  for (int mt = 0; mt < 4; ++mt) {
    const int m0 = mh * 256 + mt * 64;
    const short* qp = qbase + (size_t)mt * 64 * 640;

    // ---- QK^T swapped: acc[j][r] = S^T[n = j*16+lg*4+r][m = m0+wvi*16+lr] ----
    f4v acc[8];
#pragma unroll
    for (int j = 0; j < 8; ++j) acc[j] = (f4v)0.0f;
#pragma unroll
    for (int ks = 0; ks < 3; ++ks) {
      const int ch = (ks * 4 + lg) * 8;
      s8v qv = (ch < 80) ? *(const s8v*)&qp[(size_t)lr * 640 + ch] : (s8v)(short)0;
#pragma unroll
      for (int j = 0; j < 8; ++j) {
        s8v kv = *(const s8v*)&kT[(j * 16 + lr) * 104 + ch];
        acc[j] = mfma16(kv, qv, acc[j]);   // A = K (n-rows), B = Q (m-rows)
      }
    }

    // ---- bias + in-lane softmax (row m = m0 + wvi*16 + lr) ----
    const int m_g = m0 + wvi * 16 + lr;
    const float gyc = ((float)(m_g >> 6) * 0.25f + (0.125f - 1.f)) * 3.75f;
    const float gxc = ((float)(m_g & 63) * 0.03125f + (0.015625f - 1.f)) * 31.75f;
    float mx = -1e30f;
#pragma unroll
    for (int j = 0; j < 8; ++j) {
      f4v pyv = *(const volatile f4v*)&pynL[j * 16 + lg * 4];
      f4v pxv = *(const volatile f4v*)&pxnL[j * 16 + lg * 4];
#pragma unroll
      for (int r = 0; r < 4; ++r) {
        float gy = gyc + pyv[r], gx = gxc + pxv[r];
        float fy = floorf(gy), fx = floorf(gx);
        int iy = (int)fy, ix = (int)fx;
        float wy = gy - fy, wx = gx - fx;
        const short* t = &rpeB[iy * 132 + ix];
        float t00 = b2f(t[0]), t01 = b2f(t[1]);
        float t10 = b2f(t[132]), t11 = b2f(t[133]);
        float top = fmaf(wx, t01 - t00, t00);
        float bot = fmaf(wx, t11 - t10, t10);
        float bias = fmaf(wy, bot - top, top);
        float sv = fmaf(acc[j][r], scale, bias);
        acc[j][r] = sv;
        mx = fmaxf(mx, sv);
      }
    }
    mx = fmaxf(mx, __shfl_xor(mx, 16));
    mx = fmaxf(mx, __shfl_xor(mx, 32));
    float sm = 0.f;
#pragma unroll
    for (int j = 0; j < 8; ++j)
#pragma unroll
      for (int r = 0; r < 4; ++r) {
        float e = __expf(acc[j][r] - mx);
        acc[j][r] = e;
        sm += e;
      }
    sm += __shfl_xor(sm, 16);
    sm += __shfl_xor(sm, 32);
    const float inv = 1.f / sm;
    // P write: row m = wvi*16+lr, 4 consecutive n per j -> b64 writes
#pragma unroll
    for (int j = 0; j < 8; ++j) {
      s4v pk;
#pragma unroll
      for (int r = 0; r < 4; ++r) pk[r] = f2b(acc[j][r] * inv);
      *(s4v*)&pT[(wvi * 16 + lr) * 136 + j * 16 + lg * 4] = pk;
    }

    // ---- PV: P from LDS (same-wave RAW), V from global (volatile = no hoist) ----
    f4v pacc[5];
#pragma unroll
    for (int t = 0; t < 5; ++t) pacc[t] = (f4v)0.0f;
#pragma unroll
    for (int ks = 0; ks < 4; ++ks) {
      s8v pa = *(const s8v*)&pT[(wvi * 16 + lr) * 136 + ks * 32 + lg * 8];
#pragma unroll
      for (int ct = 0; ct < 5; ++ct) {
        s8v vb = *(const volatile s8v*)&vp[(size_t)(ct * 16 + lr) * 128 + ks * 32 + lg * 8];
        pacc[ct] = mfma16(pa, vb, pacc[ct]);
      }
    }
    short* aop = aobase + (size_t)mt * 64 * 640;
#pragma unroll
    for (int ct = 0; ct < 5; ++ct)
#pragma unroll
      for (int r = 0; r < 4; ++r)
        aop[(size_t)(lg * 4 + r) * 640 + ct * 16 + lr] = f2b(pacc[ct][r]);
  }
}

// =============================== launcher ===============================
extern "C" void kernel_launch(void* const* d_in, const int* in_sizes, int n_in,
                              void* d_out, int out_size, void* d_ws, size_t ws_size,
                              hipStream_t stream) {
  (void)in_sizes; (void)n_in; (void)out_size; (void)ws_size;
  const float* x   = (const float*)d_in[0];
  const float* y   = (const float*)d_in[1];
  const float* w1  = (const float*)d_in[2];
  const float* b1  = (const float*)d_in[3];
  const float* lng = (const float*)d_in[4];
  const float* lnb = (const float*)d_in[5];
  const float* w2  = (const float*)d_in[6];
  const float* qw  = (const float*)d_in[7];
  const float* qb  = (const float*)d_in[8];
  const float* kw  = (const float*)d_in[9];
  const float* kb  = (const float*)d_in[10];
  const float* vw  = (const float*)d_in[11];
  const float* vb  = (const float*)d_in[12];
  const float* ow  = (const float*)d_in[13];
  const float* ob  = (const float*)d_in[14];
  const float* rpe = (const float*)d_in[15];
  float* out = (float*)d_out;
  float* pos_out = out + 10485760;
  float* ref_out = out + 10518528;

  char* base = (char*)d_ws;
  size_t off = 0;
  auto take = [&](size_t bytes) {
    char* pch = base + off;
    off = (off + bytes + 255) & ~(size_t)255;
    return pch;
  };
  float* pos   = (float*)take(131072);        // [128][128][2] f32
  short* x_t   = (short*)take(20971520);      // [32][512][640] bf16
  short* y_t   = (short*)take(20971520);      // [32][512][640] bf16
  short* q_t   = (short*)take(20971520);      // [32][512][640] bf16
  short* qw_bf = (short*)take(819200);
  short* kw_bf = (short*)take(819200);
  short* vw_bf = (short*)take(819200);
  short* ow_bf = (short*)take(819200);
  short* xs_bf = (short*)take(5242880);       // [32][128][640] bf16
  short* k_t   = (short*)take(5242880);       // [32][128][640] bf16
  short* v_bf  = (short*)take(5242880);       // [32][640][128] bf16
  char*  regB  = take(20971520);              // co (f32 [128][128][320]) then ao_t
  float* co    = (float*)regB;
  short* ao_t  = (short*)regB;                // [32][512][640] bf16

  // transposes (x and y in one launch) + batched weight converts
  transpose_k<<<dim3(20, 16, 64), dim3(32, 8), 0, stream>>>(x, y, x_t, y_t);
  cvtw4_k<<<dim3(1600, 4), 256, 0, stream>>>(qw, kw, vw, ow, qw_bf, kw_bf, vw_bf, ow_bf);

  // offset network
  conv_off_k<<<dim3(40, 128), 256, 0, stream>>>(x, y, w1, b1, co);
  ln_proj_k<<<dim3(32, 128), 256, 0, stream>>>(co, lng, lnb, w2, pos, pos_out, ref_out);

  // deformable sampling
  sample_k<<<dim3(16, 128), 256, 0, stream>>>(x_t, pos, xs_bf);

  // projections (128^2-tile global_load_lds GEMMs; all operands [row][K])
  gemm128_k<true,  false><<<dim3(4, 5, 32), 256, 0, stream>>>(y_t, 512LL * 640, qw_bf, 0LL, qb, q_t, 512, 640, 640);
  gemm128_k<true,  false><<<dim3(1, 5, 32), 256, 0, stream>>>(xs_bf, 128LL * 640, kw_bf, 0LL, kb, k_t, 128, 640, 640);
  gemm128_k<false, false><<<dim3(5, 1, 32), 256, 0, stream>>>(vw_bf, 0LL, xs_bf, 128LL * 640, vb, v_bf, 640, 640, 128);

  // fused attention (QK^T + bias + softmax + PV); 512 blocks, 4 m-tiles each
  qkpv_k<<<dim3(256, 2), 256, 0, stream>>>(q_t, k_t, v_bf, pos, rpe, ao_t);

  // output projection (f32 out)
  gemm128_k<false, true><<<dim3(5, 4, 32), 256, 0, stream>>>(ow_bf, 0LL, ao_t, 512LL * 640, ob, out, 640, 640, 512);
}

// Round 14
// 250.427 us; speedup vs baseline: 1.0835x; 1.0835x over previous
//
#include <hip/hip_runtime.h>

#define DI static __device__ __forceinline__

typedef __attribute__((ext_vector_type(8))) short s8v;
typedef __attribute__((ext_vector_type(4))) short s4v;
typedef __attribute__((ext_vector_type(4))) float f4v;

DI short f2b(float x) {
  unsigned u = __builtin_bit_cast(unsigned, x);
  u = (u + 0x7fffu + ((u >> 16) & 1u)) >> 16;
  return (short)u;
}
DI float b2f(short s) {
  unsigned u = ((unsigned)(unsigned short)s) << 16;
  return __builtin_bit_cast(float, u);
}
DI f4v mfma16(s8v a, s8v b, f4v c) {
  return __builtin_amdgcn_mfma_f32_16x16x32_bf16(a, b, c, 0, 0, 0);
}
DI void gload16(const short* g, short* l) {
  __builtin_amdgcn_global_load_lds(
      (const __attribute__((address_space(1))) unsigned*)g,
      (__attribute__((address_space(3))) unsigned*)l, 16, 0, 0);
}

// ---------------- batched f32 -> bf16 convert (4 weight matrices) ----------------
__global__ __launch_bounds__(256) void cvtw4_k(
    const float* __restrict__ s0, const float* __restrict__ s1,
    const float* __restrict__ s2, const float* __restrict__ s3,
    short* __restrict__ d0, short* __restrict__ d1,
    short* __restrict__ d2, short* __restrict__ d3) {
  int w = blockIdx.y;
  const float* s = (w == 0) ? s0 : (w == 1) ? s1 : (w == 2) ? s2 : s3;
  short* d = (w == 0) ? d0 : (w == 1) ? d1 : (w == 2) ? d2 : d3;
  int i = blockIdx.x * 256 + threadIdx.x;
  d[i] = f2b(s[i]);
}

// ---------------- grouped 9x9 stride-2 conv (offset net part 1) ----------------
__global__ __launch_bounds__(256) void conv_off_k(
    const float* __restrict__ x, const float* __restrict__ y,
    const float* __restrict__ w1, const float* __restrict__ b1,
    float* __restrict__ co)
{
  __shared__ float si[8 * 8 * 84 + 84];   // 21.8 kB; zero row at offset 5376
  const int cc = blockIdx.x;
  const int n  = blockIdx.y;
  const int b = n >> 2, g = n & 3;
  const int c0 = cc * 8;
  const float* src = (g < 2 ? x : y) + ((size_t)b * 640 + (g & 1) * 320 + c0) * 512;
  const int tid = threadIdx.x;
  float* const zb = &si[8 * 8 * 84];

  for (int i = tid; i < 512; i += 256) {
    int chrow = i >> 3, t = i & 7;
    int par = t & 1, which = t >> 1;
    int idx = (which < 2) ? which : 32 + which;
    si[chrow * 84 + par * 42 + idx] = 0.f;
  }
  for (int i = tid; i < 84; i += 256) zb[i] = 0.f;
  for (int i = tid; i < 8 * 512; i += 256) {
    int ch = i >> 9, idx = i & 511;
    int r = idx >> 6, c = idx & 63;
    int pc = c + 4;
    si[(ch * 8 + r) * 84 + (pc & 1) * 42 + (pc >> 1)] = src[(size_t)ch * 512 + idx];
  }
  __syncthreads();

  const int lane = tid & 63, wvi = tid >> 6;
  const int cl = lane & 15, rg = lane >> 4;
  const int ocs = __builtin_amdgcn_readfirstlane(c0 + 2 * wvi);
  const float* wbase = w1 + (size_t)ocs * 162;
  float a00 = 0.f, a01 = 0.f, a10 = 0.f, a11 = 0.f;
#pragma unroll
  for (int ic = 0; ic < 2; ++ic) {
    const float* chb = &si[(2 * wvi + ic) * 8 * 84];
#pragma unroll
    for (int kh = 0; kh < 9; ++kh) {
      const int row = 2 * rg + kh - 4;
      const float* rp = ((unsigned)row < 8u) ? (chb + row * 84) : zb;
      float ev[6], ov[5];
#pragma unroll
      for (int t = 0; t < 6; ++t) ev[t] = rp[2 * cl + t];
#pragma unroll
      for (int t = 0; t < 5; ++t) ov[t] = rp[42 + 2 * cl + t];
      const float* wv0 = wbase + ic * 81 + kh * 9;
      const float* wv1 = wv0 + 162;
#pragma unroll
      for (int kw = 0; kw < 9; ++kw) {
        float w0 = wv0[kw], w1v = wv1[kw];
        int j = kw >> 1;
        float v0 = (kw & 1) ? ov[j] : ev[j];
        float v1 = (kw & 1) ? ov[j + 1] : ev[j + 1];
        a00 = fmaf(v0, w0, a00);
        a01 = fmaf(v1, w0, a01);
        a10 = fmaf(v0, w1v, a10);
        a11 = fmaf(v1, w1v, a11);
      }
    }
  }
  const float bv0 = b1[ocs], bv1 = b1[ocs + 1];
  const int s0 = rg * 32 + 2 * cl;
  float2 vA = {a00 + bv0, a10 + bv1};
  float2 vB = {a01 + bv0, a11 + bv1};
  *(float2*)&co[((size_t)n * 128 + s0) * 320 + ocs] = vA;
  *(float2*)&co[((size_t)n * 128 + s0 + 1) * 320 + ocs] = vB;
}

// ---------------- LN + GELU + proj + tanh -> pos (offset net part 2) ----------------
__global__ __launch_bounds__(256) void ln_proj_k(
    const float* __restrict__ co, const float* __restrict__ lng,
    const float* __restrict__ lnb, const float* __restrict__ w2,
    float* __restrict__ pos, float* __restrict__ pos_out, float* __restrict__ ref_out)
{
  const int n = blockIdx.y;
  const int wvi = threadIdx.x >> 6, lane = threadIdx.x & 63;
  const int s = blockIdx.x * 4 + wvi;
  const float* cp = co + ((size_t)n * 128 + s) * 320;
  float v[5], gw[5], gb[5], p0[5], p1[5];
#pragma unroll
  for (int t = 0; t < 5; ++t) {
    int ch = lane + 64 * t;
    v[t] = cp[ch]; gw[t] = lng[ch]; gb[t] = lnb[ch];
    p0[t] = w2[ch]; p1[t] = w2[320 + ch];
  }
  float s1 = 0.f, s2 = 0.f;
#pragma unroll
  for (int t = 0; t < 5; ++t) { s1 += v[t]; s2 += v[t] * v[t]; }
#pragma unroll
  for (int o = 32; o; o >>= 1) { s1 += __shfl_xor(s1, o); s2 += __shfl_xor(s2, o); }
  float mu = s1 * (1.f / 320.f);
  float var = s2 * (1.f / 320.f) - mu * mu;
  float rstd = rsqrtf(var + 1e-5f);
  float d0 = 0.f, d1 = 0.f;
#pragma unroll
  for (int t = 0; t < 5; ++t) {
    float xn = (v[t] - mu) * rstd * gw[t] + gb[t];
    float ge = 0.5f * xn * (1.f + erff(xn * 0.70710678118654752f));
    d0 = fmaf(ge, p0[t], d0);
    d1 = fmaf(ge, p1[t], d1);
  }
#pragma unroll
  for (int o = 32; o; o >>= 1) { d0 += __shfl_xor(d0, o); d1 += __shfl_xor(d1, o); }
  if (lane == 0) {
    float oy = tanhf(d0) * 0.5f;
    float ox = tanhf(d1) * 0.0625f;
    int hk = s >> 5, wk = s & 31;
    float ry = ((float)hk + 0.5f) * 0.5f - 1.f;
    float rx = ((float)wk + 0.5f) * 0.0625f - 1.f;
    float py = oy + ry, px = ox + rx;
    size_t o2 = ((size_t)n * 128 + s) * 2;
    pos[o2] = py;     pos[o2 + 1] = px;
    pos_out[o2] = py; pos_out[o2 + 1] = px;
    ref_out[o2] = ry; ref_out[o2 + 1] = rx;
  }
}

// ---------------- transpose both x,y: [b][c][hw] f32 -> [b][hw][c] bf16 ----------------
__global__ __launch_bounds__(256) void transpose_k(
    const float* __restrict__ x, const float* __restrict__ y,
    short* __restrict__ xt, short* __restrict__ yt) {
  __shared__ float tile[32][33];
  const int ct = blockIdx.x, st = blockIdx.y, z = blockIdx.z;
  const int b = z & 31;
  const float* srcm = (z < 32) ? x : y;
  short* dstm = (z < 32) ? xt : yt;
  const int tx = threadIdx.x, ty = threadIdx.y;
  const float* src = srcm + ((size_t)b * 640 + ct * 32) * 512 + st * 32;
#pragma unroll
  for (int k2 = 0; k2 < 4; ++k2)
    tile[ty + 8 * k2][tx] = src[(size_t)(ty + 8 * k2) * 512 + tx];
  __syncthreads();
  short* dst = dstm + ((size_t)b * 512 + st * 32) * 640 + ct * 32;
#pragma unroll
  for (int k2 = 0; k2 < 4; ++k2)
    dst[(size_t)(ty + 8 * k2) * 640 + tx] = f2b(tile[tx][ty + 8 * k2]);
}

// ---------------- bilinear sampler: xs[b][n=128][c=640] bf16 ----------------
__global__ __launch_bounds__(256) void sample_k(const short* __restrict__ xt,
                                                const float* __restrict__ pos,
                                                short* __restrict__ xs) {
  const int sc = blockIdx.x, bg = blockIdx.y;
  const int b = bg >> 2, g = bg & 3;
  const int t = threadIdx.x;
  const int s = sc * 8 + (t >> 5);
  const int ci = t & 31;
  size_t p2 = ((size_t)bg * 128 + s) * 2;
  float py = pos[p2], px = pos[p2 + 1];
  float gx = (px + 1.f) * 32.f - 0.5f;
  float gy = (py + 1.f) * 4.f - 0.5f;
  float fx = floorf(gx), fy = floorf(gy);
  int x0 = (int)fx, y0 = (int)fy;
  float wx1 = gx - fx, wx0 = 1.f - wx1;
  float wy1 = gy - fy, wy0 = 1.f - wy1;
  int xx[2] = {x0, x0 + 1}, yy[2] = {y0, y0 + 1};
  float wxs[2] = {wx0, wx1}, wys[2] = {wy0, wy1};
  const short* basep = xt + (size_t)b * 512 * 640 + (size_t)g * 160;
  short* outp = xs + ((size_t)(b * 128 + s)) * 640 + g * 160;
#pragma unroll
  for (int kk = 0; kk < 5; ++kk) {
    int c = kk * 32 + ci;
    float acc = 0.f;
#pragma unroll
    for (int ty = 0; ty < 2; ++ty) {
      int yv = yy[ty];
      bool vy = (yv >= 0) & (yv < 8);
      int yc = min(max(yv, 0), 7);
#pragma unroll
      for (int tx = 0; tx < 2; ++tx) {
        int xv = xx[tx];
        bool vv = vy & (xv >= 0) & (xv < 64);
        int xc = min(max(xv, 0), 63);
        float val = b2f(basep[((size_t)yc * 64 + xc) * 640 + c]);
        acc += wys[ty] * wxs[tx] * (vv ? val : 0.f);
      }
    }
    outp[c] = f2b(acc);
  }
}

// ---------------- 128x128-tile MFMA GEMM with global_load_lds (m97 structure) ----
template <bool BIASN, bool OUTF32>
__global__ __launch_bounds__(256) void gemm128_k(
    const short* __restrict__ W, long long wStride,
    const short* __restrict__ X, long long xStride,
    const float* __restrict__ bias, void* __restrict__ Out,
    int M, int K, int N)
{
  __shared__ short wa[128 * 32];
  __shared__ short xb[128 * 32];
  const int m0 = blockIdx.x * 128, n0 = blockIdx.y * 128;
  const int bz = blockIdx.z;
  const short* Wp = W + (size_t)bz * wStride + (size_t)m0 * K;
  const short* Xp = X + (size_t)bz * xStride + (size_t)n0 * K;
  const int tid = threadIdx.x;
  const int lane = tid & 63;
  const int wvi = __builtin_amdgcn_readfirstlane(tid >> 6);
  const int wr = wvi >> 1, wc = wvi & 1, lr = lane & 15, lg = lane >> 4;

  const int r0 = (wvi * 16) + (lane >> 2);
  const int cb = (lane & 3) * 8;
  const short* wg0 = Wp + (size_t)r0 * K + cb;
  const short* wg1 = Wp + (size_t)(r0 + 64) * K + cb;
  const short* xg0 = Xp + (size_t)r0 * K + cb;
  const short* xg1 = Xp + (size_t)(r0 + 64) * K + cb;
  short* la0 = &wa[wvi * 512];
  short* la1 = &wa[(4 + wvi) * 512];
  short* lb0 = &xb[wvi * 512];
  short* lb1 = &xb[(4 + wvi) * 512];

  f4v acc[4][4];
#pragma unroll
  for (int i = 0; i < 4; ++i)
#pragma unroll
    for (int j = 0; j < 4; ++j) acc[i][j] = (f4v)0.0f;

  const int nk = K >> 5;
  for (int ks = 0; ks < nk; ++ks) {
    __syncthreads();
    const int ko = ks * 32;
    gload16(wg0 + ko, la0);
    gload16(wg1 + ko, la1);
    gload16(xg0 + ko, lb0);
    gload16(xg1 + ko, lb1);
    __syncthreads();
    s8v av[4], bv[4];
#pragma unroll
    for (int i = 0; i < 4; ++i)
      av[i] = *(const s8v*)&wa[(wr * 64 + i * 16 + lr) * 32 + lg * 8];
#pragma unroll
    for (int j = 0; j < 4; ++j)
      bv[j] = *(const s8v*)&xb[(wc * 64 + j * 16 + lr) * 32 + lg * 8];
#pragma unroll
    for (int i = 0; i < 4; ++i)
#pragma unroll
      for (int j = 0; j < 4; ++j)
        acc[i][j] = mfma16(av[i], bv[j], acc[i][j]);
  }

#pragma unroll
  for (int i = 0; i < 4; ++i)
#pragma unroll
    for (int j = 0; j < 4; ++j)
#pragma unroll
      for (int r = 0; r < 4; ++r) {
        int m_g = m0 + wr * 64 + i * 16 + lg * 4 + r;
        int n_g = n0 + wc * 64 + j * 16 + lr;
        float val = acc[i][j][r] + (BIASN ? bias[n_g] : bias[m_g]);
        size_t oidx = (size_t)bz * M * N + (size_t)m_g * N + n_g;
        if (OUTF32) ((float*)Out)[oidx] = val;
        else        ((short*)Out)[oidx] = f2b(val);
      }
}

// ---------------- fused QK^T + RPE bias + softmax + PV -> ao_t (bf16) -------------
// Swapped QK (lane-local softmax rows). V from global (plain loads, batched);
// per-iteration asm memory clobber defeats cross-iteration LICM (VGPR control)
// WITHOUT serializing loads (the R13 volatile mistake). bf16 RPE table.
// LDS ~50.6 kB -> 3 blocks/CU.
__global__ __launch_bounds__(256) void qkpv_k(
    const short* __restrict__ q_t, const short* __restrict__ k_t,
    const short* __restrict__ v_, const float* __restrict__ pos,
    const float* __restrict__ rpe, short* __restrict__ ao_t)
{
  __shared__ short kT[128 * 104];     // 26.6 kB
  __shared__ short pT[64 * 136];      // 17.4 kB (wave-private 16-row bands)
  __shared__ short rpeB[21 * 132];    // 5.5 kB bf16, zero-padded ring of 3
  __shared__ float pynL[128], pxnL[128];
  const int bh = blockIdx.x, mh = blockIdx.y;
  const int b = bh >> 3, h = bh & 7, g = h >> 1;
  const int bg = b * 4 + g;
  const int tid = threadIdx.x;
  const int lane = tid & 63, wvi = tid >> 6;
  const int lr = lane & 15, lg = lane >> 4;

  // ---- stage once per block ----
  for (int i = tid; i < 21 * 132; i += 256) rpeB[i] = 0;
  if (tid < 128) {
    float py = pos[(size_t)bg * 256 + tid * 2];
    float px = pos[(size_t)bg * 256 + tid * 2 + 1];
    pynL[tid] = 10.0f - py * 3.75f;
    pxnL[tid] = 66.0f - px * 31.75f;
  }
  const short* kp = k_t + (size_t)b * 128 * 640 + h * 80;
  for (int idx = tid; idx < 1280; idx += 256) {
    int row = idx / 10, cb = idx - row * 10;
    *(s8v*)&kT[row * 104 + cb * 8] = *(const s8v*)&kp[(size_t)row * 640 + cb * 8];
  }
  for (int idx = tid; idx < 384; idx += 256) {
    int row = idx / 3, cb = idx - row * 3;
    *(s8v*)&kT[row * 104 + 80 + cb * 8] = (s8v)(short)0;
  }
  __syncthreads();
  for (int i = tid; i < 15 * 127; i += 256) {
    int r = i / 127, c = i - r * 127;
    rpeB[(r + 3) * 132 + (c + 3)] = f2b(rpe[(size_t)h * (15 * 127) + i]);
  }
  __syncthreads();

  const float scale = 0.11180339887498949f;  // 80^-0.5
  const short* qbase = q_t + ((size_t)b * 512 + mh * 256 + wvi * 16) * 640 + h * 80;
  const short* vp = v_ + ((size_t)b * 640 + h * 80) * 128;
  short* aobase = ao_t + ((size_t)b * 512 + mh * 256 + wvi * 16) * 640 + h * 80;

  for (int mt = 0; mt < 4; ++mt) {
    // compiler-only barrier: blocks LICM of LDS/global loads across iterations
    // (keeps VGPR low) while leaving within-iteration load batching intact.
    asm volatile("" ::: "memory");
    const int m0 = mh * 256 + mt * 64;
    const short* qp = qbase + (size_t)mt * 64 * 640;

    // ---- QK^T swapped: acc[j][r] = S^T[n = j*16+lg*4+r][m = m0+wvi*16+lr] ----
    f4v acc[8];
#pragma unroll
    for (int j = 0; j < 8; ++j) acc[j] = (f4v)0.0f;
#pragma unroll
    for (int ks = 0; ks < 3; ++ks) {
      const int ch = (ks * 4 + lg) * 8;
      s8v qv = (ch < 80) ? *(const s8v*)&qp[(size_t)lr * 640 + ch] : (s8v)(short)0;
#pragma unroll
      for (int j = 0; j < 8; ++j) {
        s8v kv = *(const s8v*)&kT[(j * 16 + lr) * 104 + ch];
        acc[j] = mfma16(kv, qv, acc[j]);   // A = K (n-rows), B = Q (m-rows)
      }
    }

    // ---- bias + in-lane softmax (row m = m0 + wvi*16 + lr) ----
    const int m_g = m0 + wvi * 16 + lr;
    const float gyc = ((float)(m_g >> 6) * 0.25f + (0.125f - 1.f)) * 3.75f;
    const float gxc = ((float)(m_g & 63) * 0.03125f + (0.015625f - 1.f)) * 31.75f;
    float mx = -1e30f;
#pragma unroll
    for (int j = 0; j < 8; ++j) {
      f4v pyv = *(const f4v*)&pynL[j * 16 + lg * 4];
      f4v pxv = *(const f4v*)&pxnL[j * 16 + lg * 4];
#pragma unroll
      for (int r = 0; r < 4; ++r) {
        float gy = gyc + pyv[r], gx = gxc + pxv[r];
        float fy = floorf(gy), fx = floorf(gx);
        int iy = (int)fy, ix = (int)fx;
        float wy = gy - fy, wx = gx - fx;
        const short* t = &rpeB[iy * 132 + ix];
        float t00 = b2f(t[0]), t01 = b2f(t[1]);
        float t10 = b2f(t[132]), t11 = b2f(t[133]);
        float top = fmaf(wx, t01 - t00, t00);
        float bot = fmaf(wx, t11 - t10, t10);
        float bias = fmaf(wy, bot - top, top);
        float sv = fmaf(acc[j][r], scale, bias);
        acc[j][r] = sv;
        mx = fmaxf(mx, sv);
      }
    }
    mx = fmaxf(mx, __shfl_xor(mx, 16));
    mx = fmaxf(mx, __shfl_xor(mx, 32));
    float sm = 0.f;
#pragma unroll
    for (int j = 0; j < 8; ++j)
#pragma unroll
      for (int r = 0; r < 4; ++r) {
        float e = __expf(acc[j][r] - mx);
        acc[j][r] = e;
        sm += e;
      }
    sm += __shfl_xor(sm, 16);
    sm += __shfl_xor(sm, 32);
    const float inv = 1.f / sm;
    // P write: row m = wvi*16+lr, 4 consecutive n per j -> b64 writes
#pragma unroll
    for (int j = 0; j < 8; ++j) {
      s4v pk;
#pragma unroll
      for (int r = 0; r < 4; ++r) pk[r] = f2b(acc[j][r] * inv);
      *(s4v*)&pT[(wvi * 16 + lr) * 136 + j * 16 + lg * 4] = pk;
    }

    // ---- PV: P from LDS (same-wave RAW), V from global (plain, batched) ----
    f4v pacc[5];
#pragma unroll
    for (int t = 0; t < 5; ++t) pacc[t] = (f4v)0.0f;
#pragma unroll
    for (int ks = 0; ks < 4; ++ks) {
      s8v pa = *(const s8v*)&pT[(wvi * 16 + lr) * 136 + ks * 32 + lg * 8];
#pragma unroll
      for (int ct = 0; ct < 5; ++ct) {
        s8v vb = *(const s8v*)&vp[(size_t)(ct * 16 + lr) * 128 + ks * 32 + lg * 8];
        pacc[ct] = mfma16(pa, vb, pacc[ct]);
      }
    }
    short* aop = aobase + (size_t)mt * 64 * 640;
#pragma unroll
    for (int ct = 0; ct < 5; ++ct)
#pragma unroll
      for (int r = 0; r < 4; ++r)
        aop[(size_t)(lg * 4 + r) * 640 + ct * 16 + lr] = f2b(pacc[ct][r]);
  }
}

// =============================== launcher ===============================
extern "C" void kernel_launch(void* const* d_in, const int* in_sizes, int n_in,
                              void* d_out, int out_size, void* d_ws, size_t ws_size,
                              hipStream_t stream) {
  (void)in_sizes; (void)n_in; (void)out_size; (void)ws_size;
  const float* x   = (const float*)d_in[0];
  const float* y   = (const float*)d_in[1];
  const float* w1  = (const float*)d_in[2];
  const float* b1  = (const float*)d_in[3];
  const float* lng = (const float*)d_in[4];
  const float* lnb = (const float*)d_in[5];
  const float* w2  = (const float*)d_in[6];
  const float* qw  = (const float*)d_in[7];
  const float* qb  = (const float*)d_in[8];
  const float* kw  = (const float*)d_in[9];
  const float* kb  = (const float*)d_in[10];
  const float* vw  = (const float*)d_in[11];
  const float* vb  = (const float*)d_in[12];
  const float* ow  = (const float*)d_in[13];
  const float* ob  = (const float*)d_in[14];
  const float* rpe = (const float*)d_in[15];
  float* out = (float*)d_out;
  float* pos_out = out + 10485760;
  float* ref_out = out + 10518528;

  char* base = (char*)d_ws;
  size_t off = 0;
  auto take = [&](size_t bytes) {
    char* pch = base + off;
    off = (off + bytes + 255) & ~(size_t)255;
    return pch;
  };
  float* pos   = (float*)take(131072);        // [128][128][2] f32
  short* x_t   = (short*)take(20971520);      // [32][512][640] bf16
  short* y_t   = (short*)take(20971520);      // [32][512][640] bf16
  short* q_t   = (short*)take(20971520);      // [32][512][640] bf16
  short* qw_bf = (short*)take(819200);
  short* kw_bf = (short*)take(819200);
  short* vw_bf = (short*)take(819200);
  short* ow_bf = (short*)take(819200);
  short* xs_bf = (short*)take(5242880);       // [32][128][640] bf16
  short* k_t   = (short*)take(5242880);       // [32][128][640] bf16
  short* v_bf  = (short*)take(5242880);       // [32][640][128] bf16
  char*  regB  = take(20971520);              // co (f32 [128][128][320]) then ao_t
  float* co    = (float*)regB;
  short* ao_t  = (short*)regB;                // [32][512][640] bf16

  // transposes (x and y in one launch) + batched weight converts
  transpose_k<<<dim3(20, 16, 64), dim3(32, 8), 0, stream>>>(x, y, x_t, y_t);
  cvtw4_k<<<dim3(1600, 4), 256, 0, stream>>>(qw, kw, vw, ow, qw_bf, kw_bf, vw_bf, ow_bf);

  // offset network
  conv_off_k<<<dim3(40, 128), 256, 0, stream>>>(x, y, w1, b1, co);
  ln_proj_k<<<dim3(32, 128), 256, 0, stream>>>(co, lng, lnb, w2, pos, pos_out, ref_out);

  // deformable sampling
  sample_k<<<dim3(16, 128), 256, 0, stream>>>(x_t, pos, xs_bf);

  // projections (128^2-tile global_load_lds GEMMs; all operands [row][K])
  gemm128_k<true,  false><<<dim3(4, 5, 32), 256, 0, stream>>>(y_t, 512LL * 640, qw_bf, 0LL, qb, q_t, 512, 640, 640);
  gemm128_k<true,  false><<<dim3(1, 5, 32), 256, 0, stream>>>(xs_bf, 128LL * 640, kw_bf, 0LL, kb, k_t, 128, 640, 640);
  gemm128_k<false, false><<<dim3(5, 1, 32), 256, 0, stream>>>(vw_bf, 0LL, xs_bf, 128LL * 640, vb, v_bf, 640, 640, 128);

  // fused attention (QK^T + bias + softmax + PV); 512 blocks, 4 m-tiles each
  qkpv_k<<<dim3(256, 2), 256, 0, stream>>>(q_t, k_t, v_bf, pos, rpe, ao_t);

  // output projection (f32 out)
  gemm128_k<false, true><<<dim3(5, 4, 32), 256, 0, stream>>>(ow_bf, 0LL, ao_t, 512LL * 640, ob, out, 640, 640, 512);
}

// Round 15
// 215.045 us; speedup vs baseline: 1.2618x; 1.1645x over previous
//
#include <hip/hip_runtime.h>

#define DI static __device__ __forceinline__

typedef __attribute__((ext_vector_type(8))) short s8v;
typedef __attribute__((ext_vector_type(4))) short s4v;
typedef __attribute__((ext_vector_type(4))) float f4v;

DI short f2b(float x) {
  unsigned u = __builtin_bit_cast(unsigned, x);
  u = (u + 0x7fffu + ((u >> 16) & 1u)) >> 16;
  return (short)u;
}
DI float b2f(short s) {
  unsigned u = ((unsigned)(unsigned short)s) << 16;
  return __builtin_bit_cast(float, u);
}
DI f4v mfma16(s8v a, s8v b, f4v c) {
  return __builtin_amdgcn_mfma_f32_16x16x32_bf16(a, b, c, 0, 0, 0);
}
DI void gload16(const short* g, short* l) {
  __builtin_amdgcn_global_load_lds(
      (const __attribute__((address_space(1))) unsigned*)g,
      (__attribute__((address_space(3))) unsigned*)l, 16, 0, 0);
}

// ---------------- batched f32 -> bf16 convert (4 weight matrices) ----------------
__global__ __launch_bounds__(256) void cvtw4_k(
    const float* __restrict__ s0, const float* __restrict__ s1,
    const float* __restrict__ s2, const float* __restrict__ s3,
    short* __restrict__ d0, short* __restrict__ d1,
    short* __restrict__ d2, short* __restrict__ d3) {
  int w = blockIdx.y;
  const float* s = (w == 0) ? s0 : (w == 1) ? s1 : (w == 2) ? s2 : s3;
  short* d = (w == 0) ? d0 : (w == 1) ? d1 : (w == 2) ? d2 : d3;
  int i = blockIdx.x * 256 + threadIdx.x;
  d[i] = f2b(s[i]);
}

// ---------------- grouped 9x9 stride-2 conv (offset net part 1) ----------------
__global__ __launch_bounds__(256) void conv_off_k(
    const float* __restrict__ x, const float* __restrict__ y,
    const float* __restrict__ w1, const float* __restrict__ b1,
    float* __restrict__ co)
{
  __shared__ float si[8 * 8 * 84 + 84];   // 21.8 kB; zero row at offset 5376
  const int cc = blockIdx.x;
  const int n  = blockIdx.y;
  const int b = n >> 2, g = n & 3;
  const int c0 = cc * 8;
  const float* src = (g < 2 ? x : y) + ((size_t)b * 640 + (g & 1) * 320 + c0) * 512;
  const int tid = threadIdx.x;
  float* const zb = &si[8 * 8 * 84];

  for (int i = tid; i < 512; i += 256) {
    int chrow = i >> 3, t = i & 7;
    int par = t & 1, which = t >> 1;
    int idx = (which < 2) ? which : 32 + which;
    si[chrow * 84 + par * 42 + idx] = 0.f;
  }
  for (int i = tid; i < 84; i += 256) zb[i] = 0.f;
  for (int i = tid; i < 8 * 512; i += 256) {
    int ch = i >> 9, idx = i & 511;
    int r = idx >> 6, c = idx & 63;
    int pc = c + 4;
    si[(ch * 8 + r) * 84 + (pc & 1) * 42 + (pc >> 1)] = src[(size_t)ch * 512 + idx];
  }
  __syncthreads();

  const int lane = tid & 63, wvi = tid >> 6;
  const int cl = lane & 15, rg = lane >> 4;
  const int ocs = __builtin_amdgcn_readfirstlane(c0 + 2 * wvi);
  const float* wbase = w1 + (size_t)ocs * 162;
  float a00 = 0.f, a01 = 0.f, a10 = 0.f, a11 = 0.f;
#pragma unroll
  for (int ic = 0; ic < 2; ++ic) {
    const float* chb = &si[(2 * wvi + ic) * 8 * 84];
#pragma unroll
    for (int kh = 0; kh < 9; ++kh) {
      const int row = 2 * rg + kh - 4;
      const float* rp = ((unsigned)row < 8u) ? (chb + row * 84) : zb;
      float ev[6], ov[5];
#pragma unroll
      for (int t = 0; t < 6; ++t) ev[t] = rp[2 * cl + t];
#pragma unroll
      for (int t = 0; t < 5; ++t) ov[t] = rp[42 + 2 * cl + t];
      const float* wv0 = wbase + ic * 81 + kh * 9;
      const float* wv1 = wv0 + 162;
#pragma unroll
      for (int kw = 0; kw < 9; ++kw) {
        float w0 = wv0[kw], w1v = wv1[kw];
        int j = kw >> 1;
        float v0 = (kw & 1) ? ov[j] : ev[j];
        float v1 = (kw & 1) ? ov[j + 1] : ev[j + 1];
        a00 = fmaf(v0, w0, a00);
        a01 = fmaf(v1, w0, a01);
        a10 = fmaf(v0, w1v, a10);
        a11 = fmaf(v1, w1v, a11);
      }
    }
  }
  const float bv0 = b1[ocs], bv1 = b1[ocs + 1];
  const int s0 = rg * 32 + 2 * cl;
  float2 vA = {a00 + bv0, a10 + bv1};
  float2 vB = {a01 + bv0, a11 + bv1};
  *(float2*)&co[((size_t)n * 128 + s0) * 320 + ocs] = vA;
  *(float2*)&co[((size_t)n * 128 + s0 + 1) * 320 + ocs] = vB;
}

// ---------------- LN + GELU + proj + tanh -> pos (offset net part 2) ----------------
__global__ __launch_bounds__(256) void ln_proj_k(
    const float* __restrict__ co, const float* __restrict__ lng,
    const float* __restrict__ lnb, const float* __restrict__ w2,
    float* __restrict__ pos, float* __restrict__ pos_out, float* __restrict__ ref_out)
{
  const int n = blockIdx.y;
  const int wvi = threadIdx.x >> 6, lane = threadIdx.x & 63;
  const int s = blockIdx.x * 4 + wvi;
  const float* cp = co + ((size_t)n * 128 + s) * 320;
  float v[5], gw[5], gb[5], p0[5], p1[5];
#pragma unroll
  for (int t = 0; t < 5; ++t) {
    int ch = lane + 64 * t;
    v[t] = cp[ch]; gw[t] = lng[ch]; gb[t] = lnb[ch];
    p0[t] = w2[ch]; p1[t] = w2[320 + ch];
  }
  float s1 = 0.f, s2 = 0.f;
#pragma unroll
  for (int t = 0; t < 5; ++t) { s1 += v[t]; s2 += v[t] * v[t]; }
#pragma unroll
  for (int o = 32; o; o >>= 1) { s1 += __shfl_xor(s1, o); s2 += __shfl_xor(s2, o); }
  float mu = s1 * (1.f / 320.f);
  float var = s2 * (1.f / 320.f) - mu * mu;
  float rstd = rsqrtf(var + 1e-5f);
  float d0 = 0.f, d1 = 0.f;
#pragma unroll
  for (int t = 0; t < 5; ++t) {
    float xn = (v[t] - mu) * rstd * gw[t] + gb[t];
    float ge = 0.5f * xn * (1.f + erff(xn * 0.70710678118654752f));
    d0 = fmaf(ge, p0[t], d0);
    d1 = fmaf(ge, p1[t], d1);
  }
#pragma unroll
  for (int o = 32; o; o >>= 1) { d0 += __shfl_xor(d0, o); d1 += __shfl_xor(d1, o); }
  if (lane == 0) {
    float oy = tanhf(d0) * 0.5f;
    float ox = tanhf(d1) * 0.0625f;
    int hk = s >> 5, wk = s & 31;
    float ry = ((float)hk + 0.5f) * 0.5f - 1.f;
    float rx = ((float)wk + 0.5f) * 0.0625f - 1.f;
    float py = oy + ry, px = ox + rx;
    size_t o2 = ((size_t)n * 128 + s) * 2;
    pos[o2] = py;     pos[o2 + 1] = px;
    pos_out[o2] = py; pos_out[o2 + 1] = px;
    ref_out[o2] = ry; ref_out[o2 + 1] = rx;
  }
}

// ---------------- transpose both x,y: [b][c][hw] f32 -> [b][hw][c] bf16 ----------------
__global__ __launch_bounds__(256) void transpose_k(
    const float* __restrict__ x, const float* __restrict__ y,
    short* __restrict__ xt, short* __restrict__ yt) {
  __shared__ float tile[32][33];
  const int ct = blockIdx.x, st = blockIdx.y, z = blockIdx.z;
  const int b = z & 31;
  const float* srcm = (z < 32) ? x : y;
  short* dstm = (z < 32) ? xt : yt;
  const int tx = threadIdx.x, ty = threadIdx.y;
  const float* src = srcm + ((size_t)b * 640 + ct * 32) * 512 + st * 32;
#pragma unroll
  for (int k2 = 0; k2 < 4; ++k2)
    tile[ty + 8 * k2][tx] = src[(size_t)(ty + 8 * k2) * 512 + tx];
  __syncthreads();
  short* dst = dstm + ((size_t)b * 512 + st * 32) * 640 + ct * 32;
#pragma unroll
  for (int k2 = 0; k2 < 4; ++k2)
    dst[(size_t)(ty + 8 * k2) * 640 + tx] = f2b(tile[tx][ty + 8 * k2]);
}

// ---------------- bilinear sampler: xs[b][n=128][c=640] bf16 ----------------
__global__ __launch_bounds__(256) void sample_k(const short* __restrict__ xt,
                                                const float* __restrict__ pos,
                                                short* __restrict__ xs) {
  const int sc = blockIdx.x, bg = blockIdx.y;
  const int b = bg >> 2, g = bg & 3;
  const int t = threadIdx.x;
  const int s = sc * 8 + (t >> 5);
  const int ci = t & 31;
  size_t p2 = ((size_t)bg * 128 + s) * 2;
  float py = pos[p2], px = pos[p2 + 1];
  float gx = (px + 1.f) * 32.f - 0.5f;
  float gy = (py + 1.f) * 4.f - 0.5f;
  float fx = floorf(gx), fy = floorf(gy);
  int x0 = (int)fx, y0 = (int)fy;
  float wx1 = gx - fx, wx0 = 1.f - wx1;
  float wy1 = gy - fy, wy0 = 1.f - wy1;
  int xx[2] = {x0, x0 + 1}, yy[2] = {y0, y0 + 1};
  float wxs[2] = {wx0, wx1}, wys[2] = {wy0, wy1};
  const short* basep = xt + (size_t)b * 512 * 640 + (size_t)g * 160;
  short* outp = xs + ((size_t)(b * 128 + s)) * 640 + g * 160;
#pragma unroll
  for (int kk = 0; kk < 5; ++kk) {
    int c = kk * 32 + ci;
    float acc = 0.f;
#pragma unroll
    for (int ty = 0; ty < 2; ++ty) {
      int yv = yy[ty];
      bool vy = (yv >= 0) & (yv < 8);
      int yc = min(max(yv, 0), 7);
#pragma unroll
      for (int tx = 0; tx < 2; ++tx) {
        int xv = xx[tx];
        bool vv = vy & (xv >= 0) & (xv < 64);
        int xc = min(max(xv, 0), 63);
        float val = b2f(basep[((size_t)yc * 64 + xc) * 640 + c]);
        acc += wys[ty] * wxs[tx] * (vv ? val : 0.f);
      }
    }
    outp[c] = f2b(acc);
  }
}

// ---------------- 128x128-tile MFMA GEMM with global_load_lds (m97 structure) ----
template <bool BIASN, bool OUTF32>
__global__ __launch_bounds__(256) void gemm128_k(
    const short* __restrict__ W, long long wStride,
    const short* __restrict__ X, long long xStride,
    const float* __restrict__ bias, void* __restrict__ Out,
    int M, int K, int N)
{
  __shared__ short wa[128 * 32];
  __shared__ short xb[128 * 32];
  const int m0 = blockIdx.x * 128, n0 = blockIdx.y * 128;
  const int bz = blockIdx.z;
  const short* Wp = W + (size_t)bz * wStride + (size_t)m0 * K;
  const short* Xp = X + (size_t)bz * xStride + (size_t)n0 * K;
  const int tid = threadIdx.x;
  const int lane = tid & 63;
  const int wvi = __builtin_amdgcn_readfirstlane(tid >> 6);
  const int wr = wvi >> 1, wc = wvi & 1, lr = lane & 15, lg = lane >> 4;

  const int r0 = (wvi * 16) + (lane >> 2);
  const int cb = (lane & 3) * 8;
  const short* wg0 = Wp + (size_t)r0 * K + cb;
  const short* wg1 = Wp + (size_t)(r0 + 64) * K + cb;
  const short* xg0 = Xp + (size_t)r0 * K + cb;
  const short* xg1 = Xp + (size_t)(r0 + 64) * K + cb;
  short* la0 = &wa[wvi * 512];
  short* la1 = &wa[(4 + wvi) * 512];
  short* lb0 = &xb[wvi * 512];
  short* lb1 = &xb[(4 + wvi) * 512];

  f4v acc[4][4];
#pragma unroll
  for (int i = 0; i < 4; ++i)
#pragma unroll
    for (int j = 0; j < 4; ++j) acc[i][j] = (f4v)0.0f;

  const int nk = K >> 5;
  for (int ks = 0; ks < nk; ++ks) {
    __syncthreads();
    const int ko = ks * 32;
    gload16(wg0 + ko, la0);
    gload16(wg1 + ko, la1);
    gload16(xg0 + ko, lb0);
    gload16(xg1 + ko, lb1);
    __syncthreads();
    s8v av[4], bv[4];
#pragma unroll
    for (int i = 0; i < 4; ++i)
      av[i] = *(const s8v*)&wa[(wr * 64 + i * 16 + lr) * 32 + lg * 8];
#pragma unroll
    for (int j = 0; j < 4; ++j)
      bv[j] = *(const s8v*)&xb[(wc * 64 + j * 16 + lr) * 32 + lg * 8];
#pragma unroll
    for (int i = 0; i < 4; ++i)
#pragma unroll
      for (int j = 0; j < 4; ++j)
        acc[i][j] = mfma16(av[i], bv[j], acc[i][j]);
  }

#pragma unroll
  for (int i = 0; i < 4; ++i)
#pragma unroll
    for (int j = 0; j < 4; ++j)
#pragma unroll
      for (int r = 0; r < 4; ++r) {
        int m_g = m0 + wr * 64 + i * 16 + lg * 4 + r;
        int n_g = n0 + wc * 64 + j * 16 + lr;
        float val = acc[i][j][r] + (BIASN ? bias[n_g] : bias[m_g]);
        size_t oidx = (size_t)bz * M * N + (size_t)m_g * N + n_g;
        if (OUTF32) ((float*)Out)[oidx] = val;
        else        ((short*)Out)[oidx] = f2b(val);
      }
}

// ---------------- fused QK^T + RPE bias + softmax + PV -> ao_t (bf16) -------------
// R12 proven-best variant (52 us): swapped QK (lane-local softmax rows), K/V/P/rpe
// all LDS-resident, FULL loop-invariant hoisting welcomed (register-resident V +
// bias tables beat higher occupancy with reloads — R13/R14 post-mortems).
__global__ __launch_bounds__(256) void qkpv_k(
    const short* __restrict__ q_t, const short* __restrict__ k_t,
    const short* __restrict__ v_, const float* __restrict__ pos,
    const float* __restrict__ rpe, short* __restrict__ ao_t)
{
  __shared__ short kT[128 * 104];     // 26.6 kB
  __shared__ short vT[80 * 136];      // 21.8 kB
  __shared__ short pT[64 * 136];      // 17.4 kB (wave-private 16-row bands)
  __shared__ float rpeL[21 * 132];    // 11.1 kB zero-padded
  __shared__ float pynL[128], pxnL[128];
  const int bh = blockIdx.x, mh = blockIdx.y;
  const int b = bh >> 3, h = bh & 7, g = h >> 1;
  const int bg = b * 4 + g;
  const int tid = threadIdx.x;
  const int lane = tid & 63, wvi = tid >> 6;
  const int lr = lane & 15, lg = lane >> 4;

  // ---- stage once per block ----
  for (int i = tid; i < 21 * 132; i += 256) rpeL[i] = 0.f;
  if (tid < 128) {
    float py = pos[(size_t)bg * 256 + tid * 2];
    float px = pos[(size_t)bg * 256 + tid * 2 + 1];
    pynL[tid] = 10.0f - py * 3.75f;
    pxnL[tid] = 66.0f - px * 31.75f;
  }
  const short* kp = k_t + (size_t)b * 128 * 640 + h * 80;
  for (int idx = tid; idx < 1280; idx += 256) {
    int row = idx / 10, cb = idx - row * 10;
    *(s8v*)&kT[row * 104 + cb * 8] = *(const s8v*)&kp[(size_t)row * 640 + cb * 8];
  }
  for (int idx = tid; idx < 384; idx += 256) {
    int row = idx / 3, cb = idx - row * 3;
    *(s8v*)&kT[row * 104 + 80 + cb * 8] = (s8v)(short)0;
  }
  const short* vp = v_ + ((size_t)b * 640 + h * 80) * 128;
  for (int idx = tid; idx < 1280; idx += 256) {
    int row = idx >> 4, cb = idx & 15;
    *(s8v*)&vT[row * 136 + cb * 8] = *(const s8v*)&vp[(size_t)row * 128 + cb * 8];
  }
  __syncthreads();
  for (int i = tid; i < 15 * 127; i += 256) {
    int r = i / 127, c = i - r * 127;
    rpeL[(r + 3) * 132 + (c + 3)] = rpe[(size_t)h * (15 * 127) + i];
  }
  __syncthreads();

  const float scale = 0.11180339887498949f;  // 80^-0.5
  const short* qbase = q_t + ((size_t)b * 512 + mh * 256 + wvi * 16) * 640 + h * 80;
  short* aobase = ao_t + ((size_t)b * 512 + mh * 256 + wvi * 16) * 640 + h * 80;

  for (int mt = 0; mt < 4; ++mt) {
    const int m0 = mh * 256 + mt * 64;
    const short* qp = qbase + (size_t)mt * 64 * 640;

    // ---- QK^T swapped: acc[j][r] = S^T[n = j*16+lg*4+r][m = m0+wvi*16+lr] ----
    f4v acc[8];
#pragma unroll
    for (int j = 0; j < 8; ++j) acc[j] = (f4v)0.0f;
#pragma unroll
    for (int ks = 0; ks < 3; ++ks) {
      const int ch = (ks * 4 + lg) * 8;
      s8v qv = (ch < 80) ? *(const s8v*)&qp[(size_t)lr * 640 + ch] : (s8v)(short)0;
#pragma unroll
      for (int j = 0; j < 8; ++j) {
        s8v kv = *(const s8v*)&kT[(j * 16 + lr) * 104 + ch];
        acc[j] = mfma16(kv, qv, acc[j]);   // A = K (n-rows), B = Q (m-rows)
      }
    }

    // ---- bias + in-lane softmax (row m = m0 + wvi*16 + lr) ----
    const int m_g = m0 + wvi * 16 + lr;
    const float gyc = ((float)(m_g >> 6) * 0.25f + (0.125f - 1.f)) * 3.75f;
    const float gxc = ((float)(m_g & 63) * 0.03125f + (0.015625f - 1.f)) * 31.75f;
    float mx = -1e30f;
#pragma unroll
    for (int j = 0; j < 8; ++j) {
      f4v pyv = *(const f4v*)&pynL[j * 16 + lg * 4];
      f4v pxv = *(const f4v*)&pxnL[j * 16 + lg * 4];
#pragma unroll
      for (int r = 0; r < 4; ++r) {
        float gy = gyc + pyv[r], gx = gxc + pxv[r];
        float fy = floorf(gy), fx = floorf(gx);
        int iy = (int)fy, ix = (int)fx;
        float wy = gy - fy, wx = gx - fx;
        const float* t = &rpeL[iy * 132 + ix];
        float t00 = t[0], t01 = t[1], t10 = t[132], t11 = t[133];
        float top = fmaf(wx, t01 - t00, t00);
        float bot = fmaf(wx, t11 - t10, t10);
        float bias = fmaf(wy, bot - top, top);
        float sv = fmaf(acc[j][r], scale, bias);
        acc[j][r] = sv;
        mx = fmaxf(mx, sv);
      }
    }
    mx = fmaxf(mx, __shfl_xor(mx, 16));
    mx = fmaxf(mx, __shfl_xor(mx, 32));
    float sm = 0.f;
#pragma unroll
    for (int j = 0; j < 8; ++j)
#pragma unroll
      for (int r = 0; r < 4; ++r) {
        float e = __expf(acc[j][r] - mx);
        acc[j][r] = e;
        sm += e;
      }
    sm += __shfl_xor(sm, 16);
    sm += __shfl_xor(sm, 32);
    const float inv = 1.f / sm;
    // P write: row m = wvi*16+lr, 4 consecutive n per j -> b64 writes
#pragma unroll
    for (int j = 0; j < 8; ++j) {
      s4v pk;
#pragma unroll
      for (int r = 0; r < 4; ++r) pk[r] = f2b(acc[j][r] * inv);
      *(s4v*)&pT[(wvi * 16 + lr) * 136 + j * 16 + lg * 4] = pk;
    }

    // ---- PV: P + V from LDS (same-wave RAW on pT) ----
    f4v pacc[5];
#pragma unroll
    for (int t = 0; t < 5; ++t) pacc[t] = (f4v)0.0f;
#pragma unroll
    for (int ks = 0; ks < 4; ++ks) {
      s8v pa = *(const s8v*)&pT[(wvi * 16 + lr) * 136 + ks * 32 + lg * 8];
#pragma unroll
      for (int ct = 0; ct < 5; ++ct) {
        s8v vb = *(const s8v*)&vT[(ct * 16 + lr) * 136 + ks * 32 + lg * 8];
        pacc[ct] = mfma16(pa, vb, pacc[ct]);
      }
    }
    short* aop = aobase + (size_t)mt * 64 * 640;
#pragma unroll
    for (int ct = 0; ct < 5; ++ct)
#pragma unroll
      for (int r = 0; r < 4; ++r)
        aop[(size_t)(lg * 4 + r) * 640 + ct * 16 + lr] = f2b(pacc[ct][r]);
  }
}

// =============================== launcher ===============================
extern "C" void kernel_launch(void* const* d_in, const int* in_sizes, int n_in,
                              void* d_out, int out_size, void* d_ws, size_t ws_size,
                              hipStream_t stream) {
  (void)in_sizes; (void)n_in; (void)out_size; (void)ws_size;
  const float* x   = (const float*)d_in[0];
  const float* y   = (const float*)d_in[1];
  const float* w1  = (const float*)d_in[2];
  const float* b1  = (const float*)d_in[3];
  const float* lng = (const float*)d_in[4];
  const float* lnb = (const float*)d_in[5];
  const float* w2  = (const float*)d_in[6];
  const float* qw  = (const float*)d_in[7];
  const float* qb  = (const float*)d_in[8];
  const float* kw  = (const float*)d_in[9];
  const float* kb  = (const float*)d_in[10];
  const float* vw  = (const float*)d_in[11];
  const float* vb  = (const float*)d_in[12];
  const float* ow  = (const float*)d_in[13];
  const float* ob  = (const float*)d_in[14];
  const float* rpe = (const float*)d_in[15];
  float* out = (float*)d_out;
  float* pos_out = out + 10485760;
  float* ref_out = out + 10518528;

  char* base = (char*)d_ws;
  size_t off = 0;
  auto take = [&](size_t bytes) {
    char* pch = base + off;
    off = (off + bytes + 255) & ~(size_t)255;
    return pch;
  };
  float* pos   = (float*)take(131072);        // [128][128][2] f32
  short* x_t   = (short*)take(20971520);      // [32][512][640] bf16
  short* y_t   = (short*)take(20971520);      // [32][512][640] bf16
  short* q_t   = (short*)take(20971520);      // [32][512][640] bf16
  short* qw_bf = (short*)take(819200);
  short* kw_bf = (short*)take(819200);
  short* vw_bf = (short*)take(819200);
  short* ow_bf = (short*)take(819200);
  short* xs_bf = (short*)take(5242880);       // [32][128][640] bf16
  short* k_t   = (short*)take(5242880);       // [32][128][640] bf16
  short* v_bf  = (short*)take(5242880);       // [32][640][128] bf16
  char*  regB  = take(20971520);              // co (f32 [128][128][320]) then ao_t
  float* co    = (float*)regB;
  short* ao_t  = (short*)regB;                // [32][512][640] bf16

  // transposes (x and y in one launch) + batched weight converts
  transpose_k<<<dim3(20, 16, 64), dim3(32, 8), 0, stream>>>(x, y, x_t, y_t);
  cvtw4_k<<<dim3(1600, 4), 256, 0, stream>>>(qw, kw, vw, ow, qw_bf, kw_bf, vw_bf, ow_bf);

  // offset network
  conv_off_k<<<dim3(40, 128), 256, 0, stream>>>(x, y, w1, b1, co);
  ln_proj_k<<<dim3(32, 128), 256, 0, stream>>>(co, lng, lnb, w2, pos, pos_out, ref_out);

  // deformable sampling
  sample_k<<<dim3(16, 128), 256, 0, stream>>>(x_t, pos, xs_bf);

  // projections (128^2-tile global_load_lds GEMMs; all operands [row][K])
  gemm128_k<true,  false><<<dim3(4, 5, 32), 256, 0, stream>>>(y_t, 512LL * 640, qw_bf, 0LL, qb, q_t, 512, 640, 640);
  gemm128_k<true,  false><<<dim3(1, 5, 32), 256, 0, stream>>>(xs_bf, 128LL * 640, kw_bf, 0LL, kb, k_t, 128, 640, 640);
  gemm128_k<false, false><<<dim3(5, 1, 32), 256, 0, stream>>>(vw_bf, 0LL, xs_bf, 128LL * 640, vb, v_bf, 640, 640, 128);

  // fused attention (QK^T + bias + softmax + PV); 512 blocks, 4 m-tiles each
  qkpv_k<<<dim3(256, 2), 256, 0, stream>>>(q_t, k_t, v_bf, pos, rpe, ao_t);

  // output projection (f32 out)
  gemm128_k<false, true><<<dim3(5, 4, 32), 256, 0, stream>>>(ow_bf, 0LL, ao_t, 512LL * 640, ob, out, 640, 640, 512);
}

// Round 16
// 208.186 us; speedup vs baseline: 1.3033x; 1.0329x over previous
//
#include <hip/hip_runtime.h>

#define DI static __device__ __forceinline__

typedef __attribute__((ext_vector_type(8))) short s8v;
typedef __attribute__((ext_vector_type(4))) short s4v;
typedef __attribute__((ext_vector_type(4))) float f4v;

DI short f2b(float x) {
  unsigned u = __builtin_bit_cast(unsigned, x);
  u = (u + 0x7fffu + ((u >> 16) & 1u)) >> 16;
  return (short)u;
}
DI float b2f(short s) {
  unsigned u = ((unsigned)(unsigned short)s) << 16;
  return __builtin_bit_cast(float, u);
}
DI f4v mfma16(s8v a, s8v b, f4v c) {
  return __builtin_amdgcn_mfma_f32_16x16x32_bf16(a, b, c, 0, 0, 0);
}
DI void gload16(const short* g, short* l) {
  __builtin_amdgcn_global_load_lds(
      (const __attribute__((address_space(1))) unsigned*)g,
      (__attribute__((address_space(3))) unsigned*)l, 16, 0, 0);
}

// ---------------- batched f32 -> bf16 convert (4 weight matrices) ----------------
__global__ __launch_bounds__(256) void cvtw4_k(
    const float* __restrict__ s0, const float* __restrict__ s1,
    const float* __restrict__ s2, const float* __restrict__ s3,
    short* __restrict__ d0, short* __restrict__ d1,
    short* __restrict__ d2, short* __restrict__ d3) {
  int w = blockIdx.y;
  const float* s = (w == 0) ? s0 : (w == 1) ? s1 : (w == 2) ? s2 : s3;
  short* d = (w == 0) ? d0 : (w == 1) ? d1 : (w == 2) ? d2 : d3;
  int i = blockIdx.x * 256 + threadIdx.x;
  d[i] = f2b(s[i]);
}

// ---------------- grouped 9x9 stride-2 conv (offset net part 1) ----------------
__global__ __launch_bounds__(256) void conv_off_k(
    const float* __restrict__ x, const float* __restrict__ y,
    const float* __restrict__ w1, const float* __restrict__ b1,
    float* __restrict__ co)
{
  __shared__ float si[8 * 8 * 84 + 84];   // 21.8 kB; zero row at offset 5376
  const int cc = blockIdx.x;
  const int n  = blockIdx.y;
  const int b = n >> 2, g = n & 3;
  const int c0 = cc * 8;
  const float* src = (g < 2 ? x : y) + ((size_t)b * 640 + (g & 1) * 320 + c0) * 512;
  const int tid = threadIdx.x;
  float* const zb = &si[8 * 8 * 84];

  for (int i = tid; i < 512; i += 256) {
    int chrow = i >> 3, t = i & 7;
    int par = t & 1, which = t >> 1;
    int idx = (which < 2) ? which : 32 + which;
    si[chrow * 84 + par * 42 + idx] = 0.f;
  }
  for (int i = tid; i < 84; i += 256) zb[i] = 0.f;
  for (int i = tid; i < 8 * 512; i += 256) {
    int ch = i >> 9, idx = i & 511;
    int r = idx >> 6, c = idx & 63;
    int pc = c + 4;
    si[(ch * 8 + r) * 84 + (pc & 1) * 42 + (pc >> 1)] = src[(size_t)ch * 512 + idx];
  }
  __syncthreads();

  const int lane = tid & 63, wvi = tid >> 6;
  const int cl = lane & 15, rg = lane >> 4;
  const int ocs = __builtin_amdgcn_readfirstlane(c0 + 2 * wvi);
  const float* wbase = w1 + (size_t)ocs * 162;
  float a00 = 0.f, a01 = 0.f, a10 = 0.f, a11 = 0.f;
#pragma unroll
  for (int ic = 0; ic < 2; ++ic) {
    const float* chb = &si[(2 * wvi + ic) * 8 * 84];
#pragma unroll
    for (int kh = 0; kh < 9; ++kh) {
      const int row = 2 * rg + kh - 4;
      const float* rp = ((unsigned)row < 8u) ? (chb + row * 84) : zb;
      float ev[6], ov[5];
#pragma unroll
      for (int t = 0; t < 6; ++t) ev[t] = rp[2 * cl + t];
#pragma unroll
      for (int t = 0; t < 5; ++t) ov[t] = rp[42 + 2 * cl + t];
      const float* wv0 = wbase + ic * 81 + kh * 9;
      const float* wv1 = wv0 + 162;
#pragma unroll
      for (int kw = 0; kw < 9; ++kw) {
        float w0 = wv0[kw], w1v = wv1[kw];
        int j = kw >> 1;
        float v0 = (kw & 1) ? ov[j] : ev[j];
        float v1 = (kw & 1) ? ov[j + 1] : ev[j + 1];
        a00 = fmaf(v0, w0, a00);
        a01 = fmaf(v1, w0, a01);
        a10 = fmaf(v0, w1v, a10);
        a11 = fmaf(v1, w1v, a11);
      }
    }
  }
  const float bv0 = b1[ocs], bv1 = b1[ocs + 1];
  const int s0 = rg * 32 + 2 * cl;
  float2 vA = {a00 + bv0, a10 + bv1};
  float2 vB = {a01 + bv0, a11 + bv1};
  *(float2*)&co[((size_t)n * 128 + s0) * 320 + ocs] = vA;
  *(float2*)&co[((size_t)n * 128 + s0 + 1) * 320 + ocs] = vB;
}

// ---------------- LN + GELU + proj + tanh -> pos (offset net part 2) ----------------
__global__ __launch_bounds__(256) void ln_proj_k(
    const float* __restrict__ co, const float* __restrict__ lng,
    const float* __restrict__ lnb, const float* __restrict__ w2,
    float* __restrict__ pos, float* __restrict__ pos_out, float* __restrict__ ref_out)
{
  const int n = blockIdx.y;
  const int wvi = threadIdx.x >> 6, lane = threadIdx.x & 63;
  const int s = blockIdx.x * 4 + wvi;
  const float* cp = co + ((size_t)n * 128 + s) * 320;
  float v[5], gw[5], gb[5], p0[5], p1[5];
#pragma unroll
  for (int t = 0; t < 5; ++t) {
    int ch = lane + 64 * t;
    v[t] = cp[ch]; gw[t] = lng[ch]; gb[t] = lnb[ch];
    p0[t] = w2[ch]; p1[t] = w2[320 + ch];
  }
  float s1 = 0.f, s2 = 0.f;
#pragma unroll
  for (int t = 0; t < 5; ++t) { s1 += v[t]; s2 += v[t] * v[t]; }
#pragma unroll
  for (int o = 32; o; o >>= 1) { s1 += __shfl_xor(s1, o); s2 += __shfl_xor(s2, o); }
  float mu = s1 * (1.f / 320.f);
  float var = s2 * (1.f / 320.f) - mu * mu;
  float rstd = rsqrtf(var + 1e-5f);
  float d0 = 0.f, d1 = 0.f;
#pragma unroll
  for (int t = 0; t < 5; ++t) {
    float xn = (v[t] - mu) * rstd * gw[t] + gb[t];
    float ge = 0.5f * xn * (1.f + erff(xn * 0.70710678118654752f));
    d0 = fmaf(ge, p0[t], d0);
    d1 = fmaf(ge, p1[t], d1);
  }
#pragma unroll
  for (int o = 32; o; o >>= 1) { d0 += __shfl_xor(d0, o); d1 += __shfl_xor(d1, o); }
  if (lane == 0) {
    float oy = tanhf(d0) * 0.5f;
    float ox = tanhf(d1) * 0.0625f;
    int hk = s >> 5, wk = s & 31;
    float ry = ((float)hk + 0.5f) * 0.5f - 1.f;
    float rx = ((float)wk + 0.5f) * 0.0625f - 1.f;
    float py = oy + ry, px = ox + rx;
    size_t o2 = ((size_t)n * 128 + s) * 2;
    pos[o2] = py;     pos[o2 + 1] = px;
    pos_out[o2] = py; pos_out[o2 + 1] = px;
    ref_out[o2] = ry; ref_out[o2 + 1] = rx;
  }
}

// ---------------- transpose both x,y: [b][c][hw] f32 -> [b][hw][c] bf16 ----------------
__global__ __launch_bounds__(256) void transpose_k(
    const float* __restrict__ x, const float* __restrict__ y,
    short* __restrict__ xt, short* __restrict__ yt) {
  __shared__ float tile[32][33];
  const int ct = blockIdx.x, st = blockIdx.y, z = blockIdx.z;
  const int b = z & 31;
  const float* srcm = (z < 32) ? x : y;
  short* dstm = (z < 32) ? xt : yt;
  const int tx = threadIdx.x, ty = threadIdx.y;
  const float* src = srcm + ((size_t)b * 640 + ct * 32) * 512 + st * 32;
#pragma unroll
  for (int k2 = 0; k2 < 4; ++k2)
    tile[ty + 8 * k2][tx] = src[(size_t)(ty + 8 * k2) * 512 + tx];
  __syncthreads();
  short* dst = dstm + ((size_t)b * 512 + st * 32) * 640 + ct * 32;
#pragma unroll
  for (int k2 = 0; k2 < 4; ++k2)
    dst[(size_t)(ty + 8 * k2) * 640 + tx] = f2b(tile[tx][ty + 8 * k2]);
}

// ---------------- bilinear sampler: xs[b][n=128][c=640] bf16 ----------------
__global__ __launch_bounds__(256) void sample_k(const short* __restrict__ xt,
                                                const float* __restrict__ pos,
                                                short* __restrict__ xs) {
  const int sc = blockIdx.x, bg = blockIdx.y;
  const int b = bg >> 2, g = bg & 3;
  const int t = threadIdx.x;
  const int s = sc * 8 + (t >> 5);
  const int ci = t & 31;
  size_t p2 = ((size_t)bg * 128 + s) * 2;
  float py = pos[p2], px = pos[p2 + 1];
  float gx = (px + 1.f) * 32.f - 0.5f;
  float gy = (py + 1.f) * 4.f - 0.5f;
  float fx = floorf(gx), fy = floorf(gy);
  int x0 = (int)fx, y0 = (int)fy;
  float wx1 = gx - fx, wx0 = 1.f - wx1;
  float wy1 = gy - fy, wy0 = 1.f - wy1;
  int xx[2] = {x0, x0 + 1}, yy[2] = {y0, y0 + 1};
  float wxs[2] = {wx0, wx1}, wys[2] = {wy0, wy1};
  const short* basep = xt + (size_t)b * 512 * 640 + (size_t)g * 160;
  short* outp = xs + ((size_t)(b * 128 + s)) * 640 + g * 160;
#pragma unroll
  for (int kk = 0; kk < 5; ++kk) {
    int c = kk * 32 + ci;
    float acc = 0.f;
#pragma unroll
    for (int ty = 0; ty < 2; ++ty) {
      int yv = yy[ty];
      bool vy = (yv >= 0) & (yv < 8);
      int yc = min(max(yv, 0), 7);
#pragma unroll
      for (int tx = 0; tx < 2; ++tx) {
        int xv = xx[tx];
        bool vv = vy & (xv >= 0) & (xv < 64);
        int xc = min(max(xv, 0), 63);
        float val = b2f(basep[((size_t)yc * 64 + xc) * 640 + c]);
        acc += wys[ty] * wxs[tx] * (vv ? val : 0.f);
      }
    }
    outp[c] = f2b(acc);
  }
}

// ---------------- 128x128-tile MFMA GEMM, 2-phase double-buffered staging ----------
// T3-minimum recipe: prologue-stage buf0; per K-step {stage buf^1, ds_read+MFMA
// from buf, ONE barrier}. The compiler's pre-barrier vmcnt drain lands after the
// MFMA work, so next-tile loads overlap compute. One barrier/step instead of two.
template <bool BIASN, bool OUTF32>
__global__ __launch_bounds__(256) void gemm128_k(
    const short* __restrict__ W, long long wStride,
    const short* __restrict__ X, long long xStride,
    const float* __restrict__ bias, void* __restrict__ Out,
    int M, int K, int N)
{
  __shared__ short wa[2][128 * 32];
  __shared__ short xb[2][128 * 32];
  const int m0 = blockIdx.x * 128, n0 = blockIdx.y * 128;
  const int bz = blockIdx.z;
  const short* Wp = W + (size_t)bz * wStride + (size_t)m0 * K;
  const short* Xp = X + (size_t)bz * xStride + (size_t)n0 * K;
  const int tid = threadIdx.x;
  const int lane = tid & 63;
  const int wvi = __builtin_amdgcn_readfirstlane(tid >> 6);
  const int wr = wvi >> 1, wc = wvi & 1, lr = lane & 15, lg = lane >> 4;

  const int r0 = (wvi * 16) + (lane >> 2);
  const int cb = (lane & 3) * 8;
  const short* wg0 = Wp + (size_t)r0 * K + cb;
  const short* wg1 = Wp + (size_t)(r0 + 64) * K + cb;
  const short* xg0 = Xp + (size_t)r0 * K + cb;
  const short* xg1 = Xp + (size_t)(r0 + 64) * K + cb;

  f4v acc[4][4];
#pragma unroll
  for (int i = 0; i < 4; ++i)
#pragma unroll
    for (int j = 0; j < 4; ++j) acc[i][j] = (f4v)0.0f;

  const int nk = K >> 5;
  // prologue: stage K-step 0 into buf 0
  gload16(wg0, &wa[0][wvi * 512]);
  gload16(wg1, &wa[0][(4 + wvi) * 512]);
  gload16(xg0, &xb[0][wvi * 512]);
  gload16(xg1, &xb[0][(4 + wvi) * 512]);
  __syncthreads();

  int cur = 0;
  for (int ks = 0; ks < nk; ++ks) {
    if (ks + 1 < nk) {
      const int ko = (ks + 1) * 32;
      const int nb = cur ^ 1;
      gload16(wg0 + ko, &wa[nb][wvi * 512]);
      gload16(wg1 + ko, &wa[nb][(4 + wvi) * 512]);
      gload16(xg0 + ko, &xb[nb][wvi * 512]);
      gload16(xg1 + ko, &xb[nb][(4 + wvi) * 512]);
    }
    s8v av[4], bv[4];
#pragma unroll
    for (int i = 0; i < 4; ++i)
      av[i] = *(const s8v*)&wa[cur][(wr * 64 + i * 16 + lr) * 32 + lg * 8];
#pragma unroll
    for (int j = 0; j < 4; ++j)
      bv[j] = *(const s8v*)&xb[cur][(wc * 64 + j * 16 + lr) * 32 + lg * 8];
#pragma unroll
    for (int i = 0; i < 4; ++i)
#pragma unroll
      for (int j = 0; j < 4; ++j)
        acc[i][j] = mfma16(av[i], bv[j], acc[i][j]);
    __syncthreads();
    cur ^= 1;
  }

#pragma unroll
  for (int i = 0; i < 4; ++i)
#pragma unroll
    for (int j = 0; j < 4; ++j)
#pragma unroll
      for (int r = 0; r < 4; ++r) {
        int m_g = m0 + wr * 64 + i * 16 + lg * 4 + r;
        int n_g = n0 + wc * 64 + j * 16 + lr;
        float val = acc[i][j][r] + (BIASN ? bias[n_g] : bias[m_g]);
        size_t oidx = (size_t)bz * M * N + (size_t)m_g * N + n_g;
        if (OUTF32) ((float*)Out)[oidx] = val;
        else        ((short*)Out)[oidx] = f2b(val);
      }
}

// ---------------- fused QK^T + RPE bias + softmax + PV -> ao_t (bf16) -------------
// R12 proven-best variant (52 us): swapped QK (lane-local softmax rows), K/V/P/rpe
// all LDS-resident, FULL loop-invariant hoisting welcomed (register-resident V +
// bias tables beat higher occupancy with reloads — R13/R14 post-mortems). FROZEN.
__global__ __launch_bounds__(256) void qkpv_k(
    const short* __restrict__ q_t, const short* __restrict__ k_t,
    const short* __restrict__ v_, const float* __restrict__ pos,
    const float* __restrict__ rpe, short* __restrict__ ao_t)
{
  __shared__ short kT[128 * 104];     // 26.6 kB
  __shared__ short vT[80 * 136];      // 21.8 kB
  __shared__ short pT[64 * 136];      // 17.4 kB (wave-private 16-row bands)
  __shared__ float rpeL[21 * 132];    // 11.1 kB zero-padded
  __shared__ float pynL[128], pxnL[128];
  const int bh = blockIdx.x, mh = blockIdx.y;
  const int b = bh >> 3, h = bh & 7, g = h >> 1;
  const int bg = b * 4 + g;
  const int tid = threadIdx.x;
  const int lane = tid & 63, wvi = tid >> 6;
  const int lr = lane & 15, lg = lane >> 4;

  // ---- stage once per block ----
  for (int i = tid; i < 21 * 132; i += 256) rpeL[i] = 0.f;
  if (tid < 128) {
    float py = pos[(size_t)bg * 256 + tid * 2];
    float px = pos[(size_t)bg * 256 + tid * 2 + 1];
    pynL[tid] = 10.0f - py * 3.75f;
    pxnL[tid] = 66.0f - px * 31.75f;
  }
  const short* kp = k_t + (size_t)b * 128 * 640 + h * 80;
  for (int idx = tid; idx < 1280; idx += 256) {
    int row = idx / 10, cb = idx - row * 10;
    *(s8v*)&kT[row * 104 + cb * 8] = *(const s8v*)&kp[(size_t)row * 640 + cb * 8];
  }
  for (int idx = tid; idx < 384; idx += 256) {
    int row = idx / 3, cb = idx - row * 3;
    *(s8v*)&kT[row * 104 + 80 + cb * 8] = (s8v)(short)0;
  }
  const short* vp = v_ + ((size_t)b * 640 + h * 80) * 128;
  for (int idx = tid; idx < 1280; idx += 256) {
    int row = idx >> 4, cb = idx & 15;
    *(s8v*)&vT[row * 136 + cb * 8] = *(const s8v*)&vp[(size_t)row * 128 + cb * 8];
  }
  __syncthreads();
  for (int i = tid; i < 15 * 127; i += 256) {
    int r = i / 127, c = i - r * 127;
    rpeL[(r + 3) * 132 + (c + 3)] = rpe[(size_t)h * (15 * 127) + i];
  }
  __syncthreads();

  const float scale = 0.11180339887498949f;  // 80^-0.5
  const short* qbase = q_t + ((size_t)b * 512 + mh * 256 + wvi * 16) * 640 + h * 80;
  short* aobase = ao_t + ((size_t)b * 512 + mh * 256 + wvi * 16) * 640 + h * 80;

  for (int mt = 0; mt < 4; ++mt) {
    const int m0 = mh * 256 + mt * 64;
    const short* qp = qbase + (size_t)mt * 64 * 640;

    // ---- QK^T swapped: acc[j][r] = S^T[n = j*16+lg*4+r][m = m0+wvi*16+lr] ----
    f4v acc[8];
#pragma unroll
    for (int j = 0; j < 8; ++j) acc[j] = (f4v)0.0f;
#pragma unroll
    for (int ks = 0; ks < 3; ++ks) {
      const int ch = (ks * 4 + lg) * 8;
      s8v qv = (ch < 80) ? *(const s8v*)&qp[(size_t)lr * 640 + ch] : (s8v)(short)0;
#pragma unroll
      for (int j = 0; j < 8; ++j) {
        s8v kv = *(const s8v*)&kT[(j * 16 + lr) * 104 + ch];
        acc[j] = mfma16(kv, qv, acc[j]);   // A = K (n-rows), B = Q (m-rows)
      }
    }

    // ---- bias + in-lane softmax (row m = m0 + wvi*16 + lr) ----
    const int m_g = m0 + wvi * 16 + lr;
    const float gyc = ((float)(m_g >> 6) * 0.25f + (0.125f - 1.f)) * 3.75f;
    const float gxc = ((float)(m_g & 63) * 0.03125f + (0.015625f - 1.f)) * 31.75f;
    float mx = -1e30f;
#pragma unroll
    for (int j = 0; j < 8; ++j) {
      f4v pyv = *(const f4v*)&pynL[j * 16 + lg * 4];
      f4v pxv = *(const f4v*)&pxnL[j * 16 + lg * 4];
#pragma unroll
      for (int r = 0; r < 4; ++r) {
        float gy = gyc + pyv[r], gx = gxc + pxv[r];
        float fy = floorf(gy), fx = floorf(gx);
        int iy = (int)fy, ix = (int)fx;
        float wy = gy - fy, wx = gx - fx;
        const float* t = &rpeL[iy * 132 + ix];
        float t00 = t[0], t01 = t[1], t10 = t[132], t11 = t[133];
        float top = fmaf(wx, t01 - t00, t00);
        float bot = fmaf(wx, t11 - t10, t10);
        float bias = fmaf(wy, bot - top, top);
        float sv = fmaf(acc[j][r], scale, bias);
        acc[j][r] = sv;
        mx = fmaxf(mx, sv);
      }
    }
    mx = fmaxf(mx, __shfl_xor(mx, 16));
    mx = fmaxf(mx, __shfl_xor(mx, 32));
    float sm = 0.f;
#pragma unroll
    for (int j = 0; j < 8; ++j)
#pragma unroll
      for (int r = 0; r < 4; ++r) {
        float e = __expf(acc[j][r] - mx);
        acc[j][r] = e;
        sm += e;
      }
    sm += __shfl_xor(sm, 16);
    sm += __shfl_xor(sm, 32);
    const float inv = 1.f / sm;
    // P write: row m = wvi*16+lr, 4 consecutive n per j -> b64 writes
#pragma unroll
    for (int j = 0; j < 8; ++j) {
      s4v pk;
#pragma unroll
      for (int r = 0; r < 4; ++r) pk[r] = f2b(acc[j][r] * inv);
      *(s4v*)&pT[(wvi * 16 + lr) * 136 + j * 16 + lg * 4] = pk;
    }

    // ---- PV: P + V from LDS (same-wave RAW on pT) ----
    f4v pacc[5];
#pragma unroll
    for (int t = 0; t < 5; ++t) pacc[t] = (f4v)0.0f;
#pragma unroll
    for (int ks = 0; ks < 4; ++ks) {
      s8v pa = *(const s8v*)&pT[(wvi * 16 + lr) * 136 + ks * 32 + lg * 8];
#pragma unroll
      for (int ct = 0; ct < 5; ++ct) {
        s8v vb = *(const s8v*)&vT[(ct * 16 + lr) * 136 + ks * 32 + lg * 8];
        pacc[ct] = mfma16(pa, vb, pacc[ct]);
      }
    }
    short* aop = aobase + (size_t)mt * 64 * 640;
#pragma unroll
    for (int ct = 0; ct < 5; ++ct)
#pragma unroll
      for (int r = 0; r < 4; ++r)
        aop[(size_t)(lg * 4 + r) * 640 + ct * 16 + lr] = f2b(pacc[ct][r]);
  }
}

// =============================== launcher ===============================
extern "C" void kernel_launch(void* const* d_in, const int* in_sizes, int n_in,
                              void* d_out, int out_size, void* d_ws, size_t ws_size,
                              hipStream_t stream) {
  (void)in_sizes; (void)n_in; (void)out_size; (void)ws_size;
  const float* x   = (const float*)d_in[0];
  const float* y   = (const float*)d_in[1];
  const float* w1  = (const float*)d_in[2];
  const float* b1  = (const float*)d_in[3];
  const float* lng = (const float*)d_in[4];
  const float* lnb = (const float*)d_in[5];
  const float* w2  = (const float*)d_in[6];
  const float* qw  = (const float*)d_in[7];
  const float* qb  = (const float*)d_in[8];
  const float* kw  = (const float*)d_in[9];
  const float* kb  = (const float*)d_in[10];
  const float* vw  = (const float*)d_in[11];
  const float* vb  = (const float*)d_in[12];
  const float* ow  = (const float*)d_in[13];
  const float* ob  = (const float*)d_in[14];
  const float* rpe = (const float*)d_in[15];
  float* out = (float*)d_out;
  float* pos_out = out + 10485760;
  float* ref_out = out + 10518528;

  char* base = (char*)d_ws;
  size_t off = 0;
  auto take = [&](size_t bytes) {
    char* pch = base + off;
    off = (off + bytes + 255) & ~(size_t)255;
    return pch;
  };
  float* pos   = (float*)take(131072);        // [128][128][2] f32
  short* x_t   = (short*)take(20971520);      // [32][512][640] bf16
  short* y_t   = (short*)take(20971520);      // [32][512][640] bf16
  short* q_t   = (short*)take(20971520);      // [32][512][640] bf16
  short* qw_bf = (short*)take(819200);
  short* kw_bf = (short*)take(819200);
  short* vw_bf = (short*)take(819200);
  short* ow_bf = (short*)take(819200);
  short* xs_bf = (short*)take(5242880);       // [32][128][640] bf16
  short* k_t   = (short*)take(5242880);       // [32][128][640] bf16
  short* v_bf  = (short*)take(5242880);       // [32][640][128] bf16
  char*  regB  = take(20971520);              // co (f32 [128][128][320]) then ao_t
  float* co    = (float*)regB;
  short* ao_t  = (short*)regB;                // [32][512][640] bf16

  // transposes (x and y in one launch) + batched weight converts
  transpose_k<<<dim3(20, 16, 64), dim3(32, 8), 0, stream>>>(x, y, x_t, y_t);
  cvtw4_k<<<dim3(1600, 4), 256, 0, stream>>>(qw, kw, vw, ow, qw_bf, kw_bf, vw_bf, ow_bf);

  // offset network
  conv_off_k<<<dim3(40, 128), 256, 0, stream>>>(x, y, w1, b1, co);
  ln_proj_k<<<dim3(32, 128), 256, 0, stream>>>(co, lng, lnb, w2, pos, pos_out, ref_out);

  // deformable sampling
  sample_k<<<dim3(16, 128), 256, 0, stream>>>(x_t, pos, xs_bf);

  // projections (128^2-tile 2-phase GEMMs; all operands [row][K])
  gemm128_k<true,  false><<<dim3(4, 5, 32), 256, 0, stream>>>(y_t, 512LL * 640, qw_bf, 0LL, qb, q_t, 512, 640, 640);
  gemm128_k<true,  false><<<dim3(1, 5, 32), 256, 0, stream>>>(xs_bf, 128LL * 640, kw_bf, 0LL, kb, k_t, 128, 640, 640);
  gemm128_k<false, false><<<dim3(5, 1, 32), 256, 0, stream>>>(vw_bf, 0LL, xs_bf, 128LL * 640, vb, v_bf, 640, 640, 128);

  // fused attention (QK^T + bias + softmax + PV); 512 blocks, 4 m-tiles each
  qkpv_k<<<dim3(256, 2), 256, 0, stream>>>(q_t, k_t, v_bf, pos, rpe, ao_t);

  // output projection (f32 out)
  gemm128_k<false, true><<<dim3(5, 4, 32), 256, 0, stream>>>(ow_bf, 0LL, ao_t, 512LL * 640, ob, out, 640, 640, 512);
}

// Round 17
// 174.911 us; speedup vs baseline: 1.5513x; 1.1902x over previous
//
#include <hip/hip_runtime.h>

#define DI static __device__ __forceinline__

typedef __attribute__((ext_vector_type(8))) short s8v;
typedef __attribute__((ext_vector_type(4))) short s4v;
typedef __attribute__((ext_vector_type(4))) float f4v;

DI short f2b(float x) {
  unsigned u = __builtin_bit_cast(unsigned, x);
  u = (u + 0x7fffu + ((u >> 16) & 1u)) >> 16;
  return (short)u;
}
DI float b2f(short s) {
  unsigned u = ((unsigned)(unsigned short)s) << 16;
  return __builtin_bit_cast(float, u);
}
DI f4v mfma16(s8v a, s8v b, f4v c) {
  return __builtin_amdgcn_mfma_f32_16x16x32_bf16(a, b, c, 0, 0, 0);
}
DI void gload16(const short* g, short* l) {
  __builtin_amdgcn_global_load_lds(
      (const __attribute__((address_space(1))) unsigned*)g,
      (__attribute__((address_space(3))) unsigned*)l, 16, 0, 0);
}

// ============ 2-phase 128x128 GEMM body (device fn, runtime flags) ============
// Wp = W + bz*wStride + m0*K  (rows m0..m0+127, [row][K])
// Xp = X + bz*xStride + n0*K  (rows n0..n0+127, [row][K])
DI void gemm128_dev(const short* Wp, const short* Xp, const float* bias,
                    void* Out, int M, int K, int N, int m0, int n0, size_t obase,
                    bool biasn, bool outf32, short* wa, short* xb)
{
  const int tid = threadIdx.x;
  const int lane = tid & 63;
  const int wvi = __builtin_amdgcn_readfirstlane(tid >> 6);
  const int wr = wvi >> 1, wc = wvi & 1, lr = lane & 15, lg = lane >> 4;

  const int r0 = (wvi * 16) + (lane >> 2);
  const int cb = (lane & 3) * 8;
  const short* wg0 = Wp + (size_t)r0 * K + cb;
  const short* wg1 = Wp + (size_t)(r0 + 64) * K + cb;
  const short* xg0 = Xp + (size_t)r0 * K + cb;
  const short* xg1 = Xp + (size_t)(r0 + 64) * K + cb;

  f4v acc[4][4];
#pragma unroll
  for (int i = 0; i < 4; ++i)
#pragma unroll
    for (int j = 0; j < 4; ++j) acc[i][j] = (f4v)0.0f;

  const int nk = K >> 5;
  gload16(wg0, &wa[wvi * 512]);
  gload16(wg1, &wa[(4 + wvi) * 512]);
  gload16(xg0, &xb[wvi * 512]);
  gload16(xg1, &xb[(4 + wvi) * 512]);
  __syncthreads();

  int cur = 0;
  for (int ks = 0; ks < nk; ++ks) {
    if (ks + 1 < nk) {
      const int ko = (ks + 1) * 32;
      const int nb = cur ^ 1;
      gload16(wg0 + ko, &wa[nb * 4096 + wvi * 512]);
      gload16(wg1 + ko, &wa[nb * 4096 + (4 + wvi) * 512]);
      gload16(xg0 + ko, &xb[nb * 4096 + wvi * 512]);
      gload16(xg1 + ko, &xb[nb * 4096 + (4 + wvi) * 512]);
    }
    s8v av[4], bv[4];
#pragma unroll
    for (int i = 0; i < 4; ++i)
      av[i] = *(const s8v*)&wa[cur * 4096 + (wr * 64 + i * 16 + lr) * 32 + lg * 8];
#pragma unroll
    for (int j = 0; j < 4; ++j)
      bv[j] = *(const s8v*)&xb[cur * 4096 + (wc * 64 + j * 16 + lr) * 32 + lg * 8];
#pragma unroll
    for (int i = 0; i < 4; ++i)
#pragma unroll
      for (int j = 0; j < 4; ++j)
        acc[i][j] = mfma16(av[i], bv[j], acc[i][j]);
    __syncthreads();
    cur ^= 1;
  }

#pragma unroll
  for (int i = 0; i < 4; ++i)
#pragma unroll
    for (int j = 0; j < 4; ++j)
#pragma unroll
      for (int r = 0; r < 4; ++r) {
        int m_g = m0 + wr * 64 + i * 16 + lg * 4 + r;
        int n_g = n0 + wc * 64 + j * 16 + lr;
        float val = acc[i][j][r] + (biasn ? bias[n_g] : bias[m_g]);
        size_t oidx = obase + (size_t)m_g * N + n_g;
        if (outf32) ((float*)Out)[oidx] = val;
        else        ((short*)Out)[oidx] = f2b(val);
      }
}

// ================= PHASE 1 merged: conv_off | transpose x,y | cvt weights =========
// grid: [0,5120) conv (longest first), [5120,25600) transpose, [25600,32000) cvt.
__global__ __launch_bounds__(256) void prep_k(
    const float* __restrict__ x, const float* __restrict__ y,
    const float* __restrict__ w1, const float* __restrict__ b1,
    float* __restrict__ co, short* __restrict__ xt, short* __restrict__ yt,
    const float* __restrict__ qw, const float* __restrict__ kw,
    const float* __restrict__ vw, const float* __restrict__ ow,
    short* __restrict__ qwb, short* __restrict__ kwb,
    short* __restrict__ vwb, short* __restrict__ owb)
{
  __shared__ float smemF[8 * 8 * 84 + 84];   // conv: 21.8 kB; transpose uses first 1056
  const int bid = blockIdx.x;
  const int tid = threadIdx.x;

  if (bid < 5120) {
    // ---------------- conv_off ----------------
    const int cc = bid % 40;
    const int n  = bid / 40;
    const int b = n >> 2, g = n & 3;
    const int c0 = cc * 8;
    const float* src = (g < 2 ? x : y) + ((size_t)b * 640 + (g & 1) * 320 + c0) * 512;
    float* const si = smemF;
    float* const zb = &si[8 * 8 * 84];

    for (int i = tid; i < 512; i += 256) {
      int chrow = i >> 3, t = i & 7;
      int par = t & 1, which = t >> 1;
      int idx = (which < 2) ? which : 32 + which;
      si[chrow * 84 + par * 42 + idx] = 0.f;
    }
    for (int i = tid; i < 84; i += 256) zb[i] = 0.f;
    for (int i = tid; i < 8 * 512; i += 256) {
      int ch = i >> 9, idx = i & 511;
      int r = idx >> 6, c = idx & 63;
      int pc = c + 4;
      si[(ch * 8 + r) * 84 + (pc & 1) * 42 + (pc >> 1)] = src[(size_t)ch * 512 + idx];
    }
    __syncthreads();

    const int lane = tid & 63, wvi = tid >> 6;
    const int cl = lane & 15, rg = lane >> 4;
    const int ocs = __builtin_amdgcn_readfirstlane(c0 + 2 * wvi);
    const float* wbase = w1 + (size_t)ocs * 162;
    float a00 = 0.f, a01 = 0.f, a10 = 0.f, a11 = 0.f;
#pragma unroll
    for (int ic = 0; ic < 2; ++ic) {
      const float* chb = &si[(2 * wvi + ic) * 8 * 84];
#pragma unroll
      for (int kh = 0; kh < 9; ++kh) {
        const int row = 2 * rg + kh - 4;
        const float* rp = ((unsigned)row < 8u) ? (chb + row * 84) : zb;
        float ev[6], ov[5];
#pragma unroll
        for (int t = 0; t < 6; ++t) ev[t] = rp[2 * cl + t];
#pragma unroll
        for (int t = 0; t < 5; ++t) ov[t] = rp[42 + 2 * cl + t];
        const float* wv0 = wbase + ic * 81 + kh * 9;
        const float* wv1 = wv0 + 162;
#pragma unroll
        for (int kw2 = 0; kw2 < 9; ++kw2) {
          float w0 = wv0[kw2], w1v = wv1[kw2];
          int j = kw2 >> 1;
          float v0 = (kw2 & 1) ? ov[j] : ev[j];
          float v1 = (kw2 & 1) ? ov[j + 1] : ev[j + 1];
          a00 = fmaf(v0, w0, a00);
          a01 = fmaf(v1, w0, a01);
          a10 = fmaf(v0, w1v, a10);
          a11 = fmaf(v1, w1v, a11);
        }
      }
    }
    const float bv0 = b1[ocs], bv1 = b1[ocs + 1];
    const int s0 = rg * 32 + 2 * cl;
    float2 vA = {a00 + bv0, a10 + bv1};
    float2 vB = {a01 + bv0, a11 + bv1};
    *(float2*)&co[((size_t)n * 128 + s0) * 320 + ocs] = vA;
    *(float2*)&co[((size_t)n * 128 + s0 + 1) * 320 + ocs] = vB;
  } else if (bid < 25600) {
    // ---------------- transpose x,y ----------------
    const int t = bid - 5120;
    const int ct = t % 20, st = (t / 20) % 16, z = t / 320;
    const int b = z & 31;
    const float* srcm = (z < 32) ? x : y;
    short* dstm = (z < 32) ? xt : yt;
    const int tx = tid & 31, ty = tid >> 5;
    float* tile = smemF;               // [32][33]
    const float* src = srcm + ((size_t)b * 640 + ct * 32) * 512 + st * 32;
#pragma unroll
    for (int k2 = 0; k2 < 4; ++k2)
      tile[(ty + 8 * k2) * 33 + tx] = src[(size_t)(ty + 8 * k2) * 512 + tx];
    __syncthreads();
    short* dst = dstm + ((size_t)b * 512 + st * 32) * 640 + ct * 32;
#pragma unroll
    for (int k2 = 0; k2 < 4; ++k2)
      dst[(size_t)(ty + 8 * k2) * 640 + tx] = f2b(tile[tx * 33 + ty + 8 * k2]);
  } else {
    // ---------------- weight cvt ----------------
    const int t = bid - 25600;
    const int w = t / 1600;
    const int i = (t % 1600) * 256 + tid;
    const float* s = (w == 0) ? qw : (w == 1) ? kw : (w == 2) ? vw : ow;
    short* d = (w == 0) ? qwb : (w == 1) ? kwb : (w == 2) ? vwb : owb;
    d[i] = f2b(s[i]);
  }
}

// ---------------- LN + GELU + proj + tanh -> pos (offset net part 2) ----------------
__global__ __launch_bounds__(256) void ln_proj_k(
    const float* __restrict__ co, const float* __restrict__ lng,
    const float* __restrict__ lnb, const float* __restrict__ w2,
    float* __restrict__ pos, float* __restrict__ pos_out, float* __restrict__ ref_out)
{
  const int n = blockIdx.y;
  const int wvi = threadIdx.x >> 6, lane = threadIdx.x & 63;
  const int s = blockIdx.x * 4 + wvi;
  const float* cp = co + ((size_t)n * 128 + s) * 320;
  float v[5], gw[5], gb[5], p0[5], p1[5];
#pragma unroll
  for (int t = 0; t < 5; ++t) {
    int ch = lane + 64 * t;
    v[t] = cp[ch]; gw[t] = lng[ch]; gb[t] = lnb[ch];
    p0[t] = w2[ch]; p1[t] = w2[320 + ch];
  }
  float s1 = 0.f, s2 = 0.f;
#pragma unroll
  for (int t = 0; t < 5; ++t) { s1 += v[t]; s2 += v[t] * v[t]; }
#pragma unroll
  for (int o = 32; o; o >>= 1) { s1 += __shfl_xor(s1, o); s2 += __shfl_xor(s2, o); }
  float mu = s1 * (1.f / 320.f);
  float var = s2 * (1.f / 320.f) - mu * mu;
  float rstd = rsqrtf(var + 1e-5f);
  float d0 = 0.f, d1 = 0.f;
#pragma unroll
  for (int t = 0; t < 5; ++t) {
    float xn = (v[t] - mu) * rstd * gw[t] + gb[t];
    float ge = 0.5f * xn * (1.f + erff(xn * 0.70710678118654752f));
    d0 = fmaf(ge, p0[t], d0);
    d1 = fmaf(ge, p1[t], d1);
  }
#pragma unroll
  for (int o = 32; o; o >>= 1) { d0 += __shfl_xor(d0, o); d1 += __shfl_xor(d1, o); }
  if (lane == 0) {
    float oy = tanhf(d0) * 0.5f;
    float ox = tanhf(d1) * 0.0625f;
    int hk = s >> 5, wk = s & 31;
    float ry = ((float)hk + 0.5f) * 0.5f - 1.f;
    float rx = ((float)wk + 0.5f) * 0.0625f - 1.f;
    float py = oy + ry, px = ox + rx;
    size_t o2 = ((size_t)n * 128 + s) * 2;
    pos[o2] = py;     pos[o2 + 1] = px;
    pos_out[o2] = py; pos_out[o2 + 1] = px;
    ref_out[o2] = ry; ref_out[o2 + 1] = rx;
  }
}

// ============ PHASE 3 merged: q-proj GEMM (640 blocks first) | sampler (2048) ======
__global__ __launch_bounds__(256) void sampq_k(
    const short* __restrict__ y_t, const short* __restrict__ qw_bf,
    const float* __restrict__ qb, short* __restrict__ q_t,
    const short* __restrict__ xt, const float* __restrict__ pos,
    short* __restrict__ xs)
{
  __shared__ short wa[2 * 4096];
  __shared__ short xb[2 * 4096];
  const int bid = blockIdx.x;
  const int t = threadIdx.x;

  if (bid < 640) {
    // q-proj: Out[bz][512][640] = y_t @ qw^T ; grid (4,5,32) flattened
    const int mx = bid % 4, ny = (bid / 4) % 5, bz = bid / 20;
    const int m0 = mx * 128, n0 = ny * 128;
    const short* Wp = y_t + (size_t)bz * 512 * 640 + (size_t)m0 * 640;
    const short* Xp = qw_bf + (size_t)n0 * 640;
    gemm128_dev(Wp, Xp, qb, q_t, 512, 640, 640, m0, n0, (size_t)bz * 512 * 640,
                true, false, wa, xb);
    return;
  }
  // ---------------- bilinear sampler ----------------
  const int tt = bid - 640;
  const int sc = tt % 16, bg = tt / 16;
  const int b = bg >> 2, g = bg & 3;
  const int s = sc * 8 + (t >> 5);
  const int ci = t & 31;
  size_t p2 = ((size_t)bg * 128 + s) * 2;
  float py = pos[p2], px = pos[p2 + 1];
  float gx = (px + 1.f) * 32.f - 0.5f;
  float gy = (py + 1.f) * 4.f - 0.5f;
  float fx = floorf(gx), fy = floorf(gy);
  int x0 = (int)fx, y0 = (int)fy;
  float wx1 = gx - fx, wx0 = 1.f - wx1;
  float wy1 = gy - fy, wy0 = 1.f - wy1;
  int xx[2] = {x0, x0 + 1}, yy[2] = {y0, y0 + 1};
  float wxs[2] = {wx0, wx1}, wys[2] = {wy0, wy1};
  const short* basep = xt + (size_t)b * 512 * 640 + (size_t)g * 160;
  short* outp = xs + ((size_t)(b * 128 + s)) * 640 + g * 160;
#pragma unroll
  for (int kk = 0; kk < 5; ++kk) {
    int c = kk * 32 + ci;
    float acc = 0.f;
#pragma unroll
    for (int ty = 0; ty < 2; ++ty) {
      int yv = yy[ty];
      bool vy = (yv >= 0) & (yv < 8);
      int yc = min(max(yv, 0), 7);
#pragma unroll
      for (int tx = 0; tx < 2; ++tx) {
        int xv = xx[tx];
        bool vv = vy & (xv >= 0) & (xv < 64);
        int xc = min(max(xv, 0), 63);
        float val = b2f(basep[((size_t)yc * 64 + xc) * 640 + c]);
        acc += wys[ty] * wxs[tx] * (vv ? val : 0.f);
      }
    }
    outp[c] = f2b(acc);
  }
}

// ============ k-proj | v-proj merged (both 160 blocks of 2-phase GEMM) =============
__global__ __launch_bounds__(256) void kv_k(
    const short* __restrict__ xs_bf, const short* __restrict__ kw_bf,
    const float* __restrict__ kb, short* __restrict__ k_t,
    const short* __restrict__ vw_bf, const float* __restrict__ vb,
    short* __restrict__ v_bf)
{
  __shared__ short wa[2 * 4096];
  __shared__ short xb[2 * 4096];
  const int bid = blockIdx.x;
  if (bid < 160) {
    // k-proj: k_t[bz][128][640] = xs @ kw^T ; grid (1,5,32)
    const int ny = bid % 5, bz = bid / 5;
    const int n0 = ny * 128;
    const short* Wp = xs_bf + (size_t)bz * 128 * 640;
    const short* Xp = kw_bf + (size_t)n0 * 640;
    gemm128_dev(Wp, Xp, kb, k_t, 128, 640, 640, 0, n0, (size_t)bz * 128 * 640,
                true, false, wa, xb);
  } else {
    // v-proj: v_bf[bz][640][128] = vw @ xs^T ; grid (5,1,32)
    const int t2 = bid - 160;
    const int mx = t2 % 5, bz = t2 / 5;
    const int m0 = mx * 128;
    const short* Wp = vw_bf + (size_t)m0 * 640;
    const short* Xp = xs_bf + (size_t)bz * 128 * 640;
    gemm128_dev(Wp, Xp, vb, v_bf, 640, 640, 128, m0, 0, (size_t)bz * 640 * 128,
                false, false, wa, xb);
  }
}

// ---------------- out-proj: f32 out ----------------
__global__ __launch_bounds__(256) void gemmO_k(
    const short* __restrict__ ow_bf, const short* __restrict__ ao_t,
    const float* __restrict__ ob, float* __restrict__ out)
{
  __shared__ short wa[2 * 4096];
  __shared__ short xb[2 * 4096];
  const int mx = blockIdx.x, ny = blockIdx.y, bz = blockIdx.z;
  const int m0 = mx * 128, n0 = ny * 128;
  const short* Wp = ow_bf + (size_t)m0 * 640;
  const short* Xp = ao_t + (size_t)bz * 512 * 640 + (size_t)n0 * 640;
  gemm128_dev(Wp, Xp, ob, out, 640, 640, 512, m0, n0, (size_t)bz * 640 * 512,
              false, true, wa, xb);
}

// ---------------- fused QK^T + RPE bias + softmax + PV -> ao_t (bf16) -------------
// R12 proven-best variant (52 us). FROZEN.
__global__ __launch_bounds__(256) void qkpv_k(
    const short* __restrict__ q_t, const short* __restrict__ k_t,
    const short* __restrict__ v_, const float* __restrict__ pos,
    const float* __restrict__ rpe, short* __restrict__ ao_t)
{
  __shared__ short kT[128 * 104];     // 26.6 kB
  __shared__ short vT[80 * 136];      // 21.8 kB
  __shared__ short pT[64 * 136];      // 17.4 kB (wave-private 16-row bands)
  __shared__ float rpeL[21 * 132];    // 11.1 kB zero-padded
  __shared__ float pynL[128], pxnL[128];
  const int bh = blockIdx.x, mh = blockIdx.y;
  const int b = bh >> 3, h = bh & 7, g = h >> 1;
  const int bg = b * 4 + g;
  const int tid = threadIdx.x;
  const int lane = tid & 63, wvi = tid >> 6;
  const int lr = lane & 15, lg = lane >> 4;

  for (int i = tid; i < 21 * 132; i += 256) rpeL[i] = 0.f;
  if (tid < 128) {
    float py = pos[(size_t)bg * 256 + tid * 2];
    float px = pos[(size_t)bg * 256 + tid * 2 + 1];
    pynL[tid] = 10.0f - py * 3.75f;
    pxnL[tid] = 66.0f - px * 31.75f;
  }
  const short* kp = k_t + (size_t)b * 128 * 640 + h * 80;
  for (int idx = tid; idx < 1280; idx += 256) {
    int row = idx / 10, cb = idx - row * 10;
    *(s8v*)&kT[row * 104 + cb * 8] = *(const s8v*)&kp[(size_t)row * 640 + cb * 8];
  }
  for (int idx = tid; idx < 384; idx += 256) {
    int row = idx / 3, cb = idx - row * 3;
    *(s8v*)&kT[row * 104 + 80 + cb * 8] = (s8v)(short)0;
  }
  const short* vp = v_ + ((size_t)b * 640 + h * 80) * 128;
  for (int idx = tid; idx < 1280; idx += 256) {
    int row = idx >> 4, cb = idx & 15;
    *(s8v*)&vT[row * 136 + cb * 8] = *(const s8v*)&vp[(size_t)row * 128 + cb * 8];
  }
  __syncthreads();
  for (int i = tid; i < 15 * 127; i += 256) {
    int r = i / 127, c = i - r * 127;
    rpeL[(r + 3) * 132 + (c + 3)] = rpe[(size_t)h * (15 * 127) + i];
  }
  __syncthreads();

  const float scale = 0.11180339887498949f;  // 80^-0.5
  const short* qbase = q_t + ((size_t)b * 512 + mh * 256 + wvi * 16) * 640 + h * 80;
  short* aobase = ao_t + ((size_t)b * 512 + mh * 256 + wvi * 16) * 640 + h * 80;

  for (int mt = 0; mt < 4; ++mt) {
    const int m0 = mh * 256 + mt * 64;
    const short* qp = qbase + (size_t)mt * 64 * 640;

    f4v acc[8];
#pragma unroll
    for (int j = 0; j < 8; ++j) acc[j] = (f4v)0.0f;
#pragma unroll
    for (int ks = 0; ks < 3; ++ks) {
      const int ch = (ks * 4 + lg) * 8;
      s8v qv = (ch < 80) ? *(const s8v*)&qp[(size_t)lr * 640 + ch] : (s8v)(short)0;
#pragma unroll
      for (int j = 0; j < 8; ++j) {
        s8v kv = *(const s8v*)&kT[(j * 16 + lr) * 104 + ch];
        acc[j] = mfma16(kv, qv, acc[j]);
      }
    }

    const int m_g = m0 + wvi * 16 + lr;
    const float gyc = ((float)(m_g >> 6) * 0.25f + (0.125f - 1.f)) * 3.75f;
    const float gxc = ((float)(m_g & 63) * 0.03125f + (0.015625f - 1.f)) * 31.75f;
    float mx = -1e30f;
#pragma unroll
    for (int j = 0; j < 8; ++j) {
      f4v pyv = *(const f4v*)&pynL[j * 16 + lg * 4];
      f4v pxv = *(const f4v*)&pxnL[j * 16 + lg * 4];
#pragma unroll
      for (int r = 0; r < 4; ++r) {
        float gy = gyc + pyv[r], gx = gxc + pxv[r];
        float fy = floorf(gy), fx = floorf(gx);
        int iy = (int)fy, ix = (int)fx;
        float wy = gy - fy, wx = gx - fx;
        const float* t = &rpeL[iy * 132 + ix];
        float t00 = t[0], t01 = t[1], t10 = t[132], t11 = t[133];
        float top = fmaf(wx, t01 - t00, t00);
        float bot = fmaf(wx, t11 - t10, t10);
        float bias = fmaf(wy, bot - top, top);
        float sv = fmaf(acc[j][r], scale, bias);
        acc[j][r] = sv;
        mx = fmaxf(mx, sv);
      }
    }
    mx = fmaxf(mx, __shfl_xor(mx, 16));
    mx = fmaxf(mx, __shfl_xor(mx, 32));
    float sm = 0.f;
#pragma unroll
    for (int j = 0; j < 8; ++j)
#pragma unroll
      for (int r = 0; r < 4; ++r) {
        float e = __expf(acc[j][r] - mx);
        acc[j][r] = e;
        sm += e;
      }
    sm += __shfl_xor(sm, 16);
    sm += __shfl_xor(sm, 32);
    const float inv = 1.f / sm;
#pragma unroll
    for (int j = 0; j < 8; ++j) {
      s4v pk;
#pragma unroll
      for (int r = 0; r < 4; ++r) pk[r] = f2b(acc[j][r] * inv);
      *(s4v*)&pT[(wvi * 16 + lr) * 136 + j * 16 + lg * 4] = pk;
    }

    f4v pacc[5];
#pragma unroll
    for (int t = 0; t < 5; ++t) pacc[t] = (f4v)0.0f;
#pragma unroll
    for (int ks = 0; ks < 4; ++ks) {
      s8v pa = *(const s8v*)&pT[(wvi * 16 + lr) * 136 + ks * 32 + lg * 8];
#pragma unroll
      for (int ct = 0; ct < 5; ++ct) {
        s8v vb = *(const s8v*)&vT[(ct * 16 + lr) * 136 + ks * 32 + lg * 8];
        pacc[ct] = mfma16(pa, vb, pacc[ct]);
      }
    }
    short* aop = aobase + (size_t)mt * 64 * 640;
#pragma unroll
    for (int ct = 0; ct < 5; ++ct)
#pragma unroll
      for (int r = 0; r < 4; ++r)
        aop[(size_t)(lg * 4 + r) * 640 + ct * 16 + lr] = f2b(pacc[ct][r]);
  }
}

// =============================== launcher ===============================
extern "C" void kernel_launch(void* const* d_in, const int* in_sizes, int n_in,
                              void* d_out, int out_size, void* d_ws, size_t ws_size,
                              hipStream_t stream) {
  (void)in_sizes; (void)n_in; (void)out_size; (void)ws_size;
  const float* x   = (const float*)d_in[0];
  const float* y   = (const float*)d_in[1];
  const float* w1  = (const float*)d_in[2];
  const float* b1  = (const float*)d_in[3];
  const float* lng = (const float*)d_in[4];
  const float* lnb = (const float*)d_in[5];
  const float* w2  = (const float*)d_in[6];
  const float* qw  = (const float*)d_in[7];
  const float* qb  = (const float*)d_in[8];
  const float* kw  = (const float*)d_in[9];
  const float* kb  = (const float*)d_in[10];
  const float* vw  = (const float*)d_in[11];
  const float* vb  = (const float*)d_in[12];
  const float* ow  = (const float*)d_in[13];
  const float* ob  = (const float*)d_in[14];
  const float* rpe = (const float*)d_in[15];
  float* out = (float*)d_out;
  float* pos_out = out + 10485760;
  float* ref_out = out + 10518528;

  char* base = (char*)d_ws;
  size_t off = 0;
  auto take = [&](size_t bytes) {
    char* pch = base + off;
    off = (off + bytes + 255) & ~(size_t)255;
    return pch;
  };
  float* pos   = (float*)take(131072);        // [128][128][2] f32
  short* x_t   = (short*)take(20971520);      // [32][512][640] bf16
  short* y_t   = (short*)take(20971520);      // [32][512][640] bf16
  short* q_t   = (short*)take(20971520);      // [32][512][640] bf16
  short* qw_bf = (short*)take(819200);
  short* kw_bf = (short*)take(819200);
  short* vw_bf = (short*)take(819200);
  short* ow_bf = (short*)take(819200);
  short* xs_bf = (short*)take(5242880);       // [32][128][640] bf16
  short* k_t   = (short*)take(5242880);       // [32][128][640] bf16
  short* v_bf  = (short*)take(5242880);       // [32][640][128] bf16
  char*  regB  = take(20971520);              // co (f32 [128][128][320]) then ao_t
  float* co    = (float*)regB;
  short* ao_t  = (short*)regB;                // [32][512][640] bf16

  // PHASE 1 (merged): conv_off | transpose x,y | weight cvt — co-scheduled
  prep_k<<<32000, 256, 0, stream>>>(x, y, w1, b1, co, x_t, y_t,
                                    qw, kw, vw, ow, qw_bf, kw_bf, vw_bf, ow_bf);

  // offset net part 2
  ln_proj_k<<<dim3(32, 128), 256, 0, stream>>>(co, lng, lnb, w2, pos, pos_out, ref_out);

  // PHASE 3 (merged): q-proj GEMM | deformable sampler — co-scheduled
  sampq_k<<<2688, 256, 0, stream>>>(y_t, qw_bf, qb, q_t, x_t, pos, xs_bf);

  // k-proj | v-proj (merged)
  kv_k<<<320, 256, 0, stream>>>(xs_bf, kw_bf, kb, k_t, vw_bf, vb, v_bf);

  // fused attention
  qkpv_k<<<dim3(256, 2), 256, 0, stream>>>(q_t, k_t, v_bf, pos, rpe, ao_t);

  // output projection (f32 out)
  gemmO_k<<<dim3(5, 4, 32), 256, 0, stream>>>(ow_bf, ao_t, ob, out);
}